// Round 1
// baseline (2420.132 us; speedup 1.0000x reference)
//
#include <hip/hip_runtime.h>
#include <math.h>

#define Bn 256
#define Tn 64
#define OBSD 1000
#define NR 30
#define HD 128
#define LH 256
#define LIN 384
#define TDI 26

// output offsets (floats)
#define AM_OFF 0
#define ALS_OFF 15360
#define V_OFF 30720
#define H_OFF 30976
#define C_OFF 96512

__device__ __forceinline__ float sigm(float x){ return 1.f/(1.f+__expf(-x)); }

// 30-row dense layer: thread owns output column j, rows rh, rh+2, ... (15 rows)
__device__ __forceinline__ void dense30(
    const float* in, int istride,
    const float* __restrict__ W, int wstride, int K,
    const float* __restrict__ bias, const float* extra,
    float* outp, int ostride, bool relu, int j, int rh)
{
    float acc[15];
    #pragma unroll
    for (int i=0;i<15;i++) acc[i]=0.f;
    const float* w = W + j*wstride;
    for (int k=0;k<K;k+=4){
        float4 wv = *(const float4*)(w+k);
        #pragma unroll
        for (int i=0;i<15;i++){
            float4 xv = *(const float4*)(in + (rh+2*i)*istride + k);
            acc[i] = fmaf(wv.x,xv.x,acc[i]);
            acc[i] = fmaf(wv.y,xv.y,acc[i]);
            acc[i] = fmaf(wv.z,xv.z,acc[i]);
            acc[i] = fmaf(wv.w,xv.w,acc[i]);
        }
    }
    float bb = bias[j] + (extra ? extra[j] : 0.f);
    #pragma unroll
    for (int i=0;i<15;i++){
        float v = acc[i]+bb;
        outp[(rh+2*i)*ostride+j] = relu ? fmaxf(v,0.f) : v;
    }
}

// single-row dense: returns dot(in, W[j,:K]) + bias[j]
__device__ __forceinline__ float dense1(
    const float* in, const float* __restrict__ W,
    const float* __restrict__ bias, int K, int j)
{
    const float* w = W + j*K;
    float s = 0.f;
    for (int k=0;k<K;k+=4){
        float4 wv = *(const float4*)(w+k);
        float4 xv = *(const float4*)(in+k);
        s = fmaf(wv.x,xv.x,s); s = fmaf(wv.y,xv.y,s);
        s = fmaf(wv.z,xv.z,s); s = fmaf(wv.w,xv.w,s);
    }
    return s + bias[j];
}

__global__ __launch_bounds__(256) void k_embed(
    const float* __restrict__ obs,
    const float* __restrict__ re_w0, const float* __restrict__ re_b0,
    const float* __restrict__ re_w1, const float* __restrict__ re_b1,
    const float* __restrict__ re_w2, const float* __restrict__ re_b2,
    const float* __restrict__ me_w0, const float* __restrict__ me_b0,
    const float* __restrict__ me_w1, const float* __restrict__ me_b1,
    const float* __restrict__ me_w2, const float* __restrict__ me_b2,
    float* __restrict__ lstm_in, float* __restrict__ runner_last)
{
    __shared__ __align__(16) float x0[NR][32];
    __shared__ __align__(16) float ha[NR][HD];
    __shared__ __align__(16) float hb[NR][HD];
    __shared__ __align__(16) float m0[40];
    __shared__ __align__(16) float mh0[HD];
    __shared__ __align__(16) float mh1[HD];

    int bt = blockIdx.x, tid = threadIdx.x;
    const float* row = obs + (size_t)bt*OBSD;

    for (int idx=tid; idx<NR*32; idx+=256){
        int r = idx>>5, k = idx&31;
        x0[r][k] = (k<24) ? row[30 + r*24 + k] : row[760 + r*8 + (k-24)];
    }
    if (tid < 40) m0[tid] = (tid<30) ? row[tid] : row[720 + tid];
    __syncthreads();

    int j = tid & 127, rh = tid >> 7;
    dense30(&x0[0][0], 32, re_w0, 32, 32, re_b0, nullptr, &ha[0][0], HD, true, j, rh);
    __syncthreads();
    dense30(&ha[0][0], HD, re_w1, HD, HD, re_b1, nullptr, &hb[0][0], HD, true, j, rh);
    __syncthreads();
    dense30(&hb[0][0], HD, re_w2, HD, HD, re_b2, nullptr, &ha[0][0], HD, false, j, rh);
    if (tid < 128) mh0[j] = fmaxf(dense1(m0, me_w0, me_b0, 40, j), 0.f);
    __syncthreads();

    float* li = lstm_in + (size_t)bt*LIN;
    if (tid < 128){
        mh1[j] = fmaxf(dense1(mh0, me_w1, me_b1, HD, j), 0.f);
    } else {
        float s = 0.f, mx = -1e30f;
        #pragma unroll
        for (int r=0;r<NR;r++){ float v = ha[r][j]; s += v; mx = fmaxf(mx, v); }
        li[HD + j]   = s * (1.0f/NR);
        li[2*HD + j] = mx;
    }
    if ((bt & 63) == 63){
        int bb = bt >> 6;
        for (int idx=tid; idx<NR*HD; idx+=256)
            runner_last[(size_t)bb*NR*HD + idx] = ha[idx>>7][idx&127];
    }
    __syncthreads();
    if (tid < 128) li[j] = dense1(mh1, me_w2, me_b2, HD, j);
}

// C[M=16384, N=1024] = A[M,384] @ W[1024,384]^T + bias
__global__ __launch_bounds__(256) void k_xw(
    const float* __restrict__ A, const float* __restrict__ W,
    const float* __restrict__ bias, float* __restrict__ C)
{
    __shared__ __align__(16) float As[16][68];
    __shared__ __align__(16) float Bs[16][68];
    int tid = threadIdx.x;
    int i0 = blockIdx.x * 64;
    int j0 = blockIdx.y * 64;
    int ty = tid >> 4, tx = tid & 15;
    int li = tid >> 2, lk = (tid & 3) << 2;

    float acc[4][4];
    #pragma unroll
    for (int a=0;a<4;a++)
        #pragma unroll
        for (int b=0;b<4;b++) acc[a][b]=0.f;

    for (int k0=0; k0<LIN; k0+=16){
        float4 a4 = *(const float4*)(A + (size_t)(i0+li)*LIN + k0 + lk);
        float4 b4 = *(const float4*)(W + (size_t)(j0+li)*LIN + k0 + lk);
        As[lk+0][li]=a4.x; As[lk+1][li]=a4.y; As[lk+2][li]=a4.z; As[lk+3][li]=a4.w;
        Bs[lk+0][li]=b4.x; Bs[lk+1][li]=b4.y; Bs[lk+2][li]=b4.z; Bs[lk+3][li]=b4.w;
        __syncthreads();
        #pragma unroll
        for (int kk=0;kk<16;kk++){
            float4 av = *(const float4*)&As[kk][ty*4];
            float4 bv = *(const float4*)&Bs[kk][tx*4];
            float aa[4] = {av.x,av.y,av.z,av.w};
            float bb[4] = {bv.x,bv.y,bv.z,bv.w};
            #pragma unroll
            for (int a=0;a<4;a++)
                #pragma unroll
                for (int b=0;b<4;b++) acc[a][b] = fmaf(aa[a], bb[b], acc[a][b]);
        }
        __syncthreads();
    }
    #pragma unroll
    for (int a=0;a<4;a++){
        int r = i0 + ty*4 + a;
        #pragma unroll
        for (int b=0;b<4;b++){
            int cidx = j0 + tx*4 + b;
            C[(size_t)r*1024 + cidx] = acc[a][b] + bias[cidx];
        }
    }
}

__global__ void k_transpose(const float* __restrict__ in, float* __restrict__ out)
{
    int idx = blockIdx.x*256 + threadIdx.x;   // 262144 total
    int rowi = idx >> 8;   // 0..1023
    int k = idx & 255;
    out[k*1024 + rowi] = in[idx];
}

// one LSTM step: block = 8 batch rows x 32 hidden cols; grid = 32*8 = 256
__global__ __launch_bounds__(256) void k_lstm_step(
    const float* __restrict__ xW, const float* __restrict__ WhhT,
    const float* __restrict__ W_dt, const float* __restrict__ obs,
    const float* __restrict__ h_in, float* __restrict__ h_out,
    float* __restrict__ c, int t)
{
    __shared__ __align__(16) float hl[8][LH];
    int tid = threadIdx.x;
    int jt  = blockIdx.x & 7;
    int bt8 = blockIdx.x >> 3;
    int j = jt*32 + (tid & 31);
    int bl = tid >> 5;
    int b = bt8*8 + bl;

    for (int idx=tid; idx<8*LH; idx+=256)
        hl[idx>>8][idx&255] = h_in[(bt8*8 + (idx>>8))*LH + (idx&255)];
    __syncthreads();

    int xbase = ((b<<6) + t)<<10;
    float acc0 = xW[xbase + j];
    float acc1 = xW[xbase + 256 + j];
    float acc2 = xW[xbase + 512 + j];
    float acc3 = xW[xbase + 768 + j];
    const float* hrow = hl[bl];
    #pragma unroll 4
    for (int k=0;k<LH;k++){
        float hv = hrow[k];
        const float* wr = WhhT + (k<<10) + j;
        acc0 = fmaf(hv, wr[0],   acc0);
        acc1 = fmaf(hv, wr[256], acc1);
        acc2 = fmaf(hv, wr[512], acc2);
        acc3 = fmaf(hv, wr[768], acc3);
    }
    float d = obs[((b<<6)+t)*OBSD + TDI];
    float fi = sigm(acc0);
    float ff = sigm(acc1 + W_dt[j]*d);
    float gg = tanhf(acc2);
    float oo = sigm(acc3);
    int cidx = b*LH + j;
    float cn = fmaf(ff, c[cidx], fi*gg);
    c[cidx] = cn;
    h_out[cidx] = oo * tanhf(cn);
}

__global__ __launch_bounds__(256) void k_heads(
    const float* __restrict__ h, const float* __restrict__ cbuf,
    const float* __restrict__ rl,
    const float* __restrict__ a_w0, const float* __restrict__ a_b0,
    const float* __restrict__ a_w1, const float* __restrict__ a_b1,
    const float* __restrict__ c_w0, const float* __restrict__ c_b0,
    const float* __restrict__ c_w1, const float* __restrict__ c_b1,
    const float* __restrict__ log_std,
    float* __restrict__ out)
{
    __shared__ __align__(16) float hv[LH];
    __shared__ __align__(16) float rls[NR][HD];
    __shared__ __align__(16) float hid[NR][HD];
    __shared__ __align__(16) float dot2[HD];
    __shared__ __align__(16) float red[128];

    int b = blockIdx.x, tid = threadIdx.x;
    hv[tid] = h[b*LH + tid];
    for (int idx=tid; idx<NR*HD; idx+=256) rls[idx>>7][idx&127] = rl[(size_t)b*NR*HD + idx];
    __syncthreads();

    if (tid < 128){
        const float* w = a_w0 + tid*LIN + HD;
        float s = 0.f;
        for (int k=0;k<LH;k+=4){
            float4 wv = *(const float4*)(w+k);
            s = fmaf(wv.x,hv[k],s); s = fmaf(wv.y,hv[k+1],s);
            s = fmaf(wv.z,hv[k+2],s); s = fmaf(wv.w,hv[k+3],s);
        }
        dot2[tid] = s;
    }
    __syncthreads();

    int j = tid & 127, rh = tid >> 7;
    dense30(&rls[0][0], HD, a_w0, LIN, HD, a_b0, dot2, &hid[0][0], HD, true, j, rh);
    __syncthreads();

    if (tid < 60){
        int r = tid >> 1, o = tid & 1;
        const float* w = a_w1 + o*HD;
        float s = a_b1[o];
        for (int k=0;k<HD;k++) s = fmaf(hid[r][k], w[k], s);
        out[AM_OFF + b*60 + tid] = s;
        out[ALS_OFF + b*60 + tid] = log_std[tid];
    }

    float term = 0.f;
    if (tid < 128) term = fmaxf(dense1(hv, c_w0, c_b0, LH, tid), 0.f) * c_w1[tid];
    if (tid < 128) red[tid] = term;
    __syncthreads();
    for (int s2=64; s2>0; s2>>=1){
        if (tid < s2) red[tid] += red[tid+s2];
        __syncthreads();
    }
    if (tid == 0) out[V_OFF + b] = red[0] + c_b1[0];

    out[H_OFF + b*LH + tid] = hv[tid];
    out[C_OFF + b*LH + tid] = cbuf[b*LH + tid];
}

extern "C" void kernel_launch(void* const* d_in, const int* in_sizes, int n_in,
                              void* d_out, int out_size, void* d_ws, size_t ws_size,
                              hipStream_t stream)
{
    const float* obs   = (const float*)d_in[0];
    const float* re_w0 = (const float*)d_in[1];
    const float* re_b0 = (const float*)d_in[2];
    const float* re_w1 = (const float*)d_in[3];
    const float* re_b1 = (const float*)d_in[4];
    const float* re_w2 = (const float*)d_in[5];
    const float* re_b2 = (const float*)d_in[6];
    const float* me_w0 = (const float*)d_in[7];
    const float* me_b0 = (const float*)d_in[8];
    const float* me_w1 = (const float*)d_in[9];
    const float* me_b1 = (const float*)d_in[10];
    const float* me_w2 = (const float*)d_in[11];
    const float* me_b2 = (const float*)d_in[12];
    const float* W_ih  = (const float*)d_in[13];
    const float* b_ih  = (const float*)d_in[14];
    const float* W_hh  = (const float*)d_in[15];
    const float* W_dt  = (const float*)d_in[16];
    const float* a_w0  = (const float*)d_in[17];
    const float* a_b0  = (const float*)d_in[18];
    const float* a_w1  = (const float*)d_in[19];
    const float* a_b1  = (const float*)d_in[20];
    const float* c_w0  = (const float*)d_in[21];
    const float* c_b0  = (const float*)d_in[22];
    const float* c_w1  = (const float*)d_in[23];
    const float* c_b1  = (const float*)d_in[24];
    const float* lstd  = (const float*)d_in[25];
    float* out = (float*)d_out;

    float* ws = (float*)d_ws;
    size_t off = 0;
    float* lstm_in = ws + off; off += (size_t)16384*LIN;
    float* xW      = ws + off; off += (size_t)16384*1024;
    float* h0      = ws + off; off += (size_t)Bn*LH;
    float* h1      = ws + off; off += (size_t)Bn*LH;
    float* cb      = ws + off; off += (size_t)Bn*LH;
    float* rl      = ws + off; off += (size_t)Bn*NR*HD;
    float* WhhT    = ws + off; off += (size_t)LH*1024;

    hipMemsetAsync(h0, 0, (size_t)Bn*LH*sizeof(float), stream);
    hipMemsetAsync(cb, 0, (size_t)Bn*LH*sizeof(float), stream);

    k_transpose<<<1024, 256, 0, stream>>>(W_hh, WhhT);

    k_embed<<<16384, 256, 0, stream>>>(obs,
        re_w0, re_b0, re_w1, re_b1, re_w2, re_b2,
        me_w0, me_b0, me_w1, me_b1, me_w2, me_b2,
        lstm_in, rl);

    k_xw<<<dim3(256,16), 256, 0, stream>>>(lstm_in, W_ih, b_ih, xW);

    for (int t=0; t<Tn; t++){
        const float* hi = (t & 1) ? h1 : h0;
        float*       ho = (t & 1) ? h0 : h1;
        k_lstm_step<<<256, 256, 0, stream>>>(xW, WhhT, W_dt, obs, hi, ho, cb, t);
    }

    k_heads<<<256, 256, 0, stream>>>(h0, cb, rl,
        a_w0, a_b0, a_w1, a_b1, c_w0, c_b0, c_w1, c_b1, lstd, out);
}

// Round 2
// 925.538 us; speedup vs baseline: 2.6148x; 2.6148x over previous
//
#include <hip/hip_runtime.h>
#include <hip/hip_bf16.h>
#include <math.h>

#define Bn 256
#define Tn 64
#define OBSD 1000
#define NR 30
#define HD 128
#define LH 256
#define LIN 384
#define TDI 26

#define AM_OFF 0
#define ALS_OFF 15360
#define V_OFF 30720
#define H_OFF 30976
#define C_OFF 96512

typedef unsigned short u16;
typedef short bf16x8 __attribute__((ext_vector_type(8)));
typedef float f32x4 __attribute__((ext_vector_type(4)));

__device__ __forceinline__ float sigm(float x){ return 1.f/(1.f+__expf(-x)); }

__device__ __forceinline__ u16 f2b(float f){
    union { __hip_bfloat16 h; u16 u; } cv;
    cv.h = __float2bfloat16(f);
    return cv.u;
}

#define MFMA(a,b,c) __builtin_amdgcn_mfma_f32_16x16x32_bf16(a,b,c,0,0,0)

// ---------------- packing kernels ----------------
// pack W[N][K] (fp32, row-major [out][in]) into bf16 MFMA B-fragment order:
// frag chunk (ntile, kc): lane l holds W[ntile*16 + (l&15)][kc*32 + (l>>4)*8 + e]
__global__ void k_pack(const float* __restrict__ src, u16* __restrict__ dst,
                       int N, int K, int Kpad)
{
    int t = blockIdx.x*256 + threadIdx.x;
    if (t >= N*Kpad) return;
    int j = t / Kpad, k = t - j*Kpad;
    float v = (k < K) ? src[j*K + k] : 0.f;
    int ntile = j>>4, jr = j&15, kc = k>>5, ko = k&31;
    int lane = ((ko>>3)<<4) | jr, elem = ko&7;
    int KC = Kpad>>5;
    dst[(size_t)(((ntile*KC + kc)*64) + lane)*8 + elem] = f2b(v);
}

// W4[k][j] = {W_hh[0*256+j][k], W_hh[256+j][k], W_hh[512+j][k], W_hh[768+j][k]}
__global__ void k_packW4(const float* __restrict__ Whh, float* __restrict__ W4)
{
    int t = blockIdx.x*256 + threadIdx.x;   // 65536
    int k = t>>8, j = t&255;
    float4 v;
    v.x = Whh[(size_t)(      j)*256 + k];
    v.y = Whh[(size_t)(256 + j)*256 + k];
    v.z = Whh[(size_t)(512 + j)*256 + k];
    v.w = Whh[(size_t)(768 + j)*256 + k];
    *(float4*)(W4 + (size_t)t*4) = v;
}

// ---------------- runner embed (MFMA) ----------------
// one block per (b,t): 30(pad32)x32 -> 128 -> 128 -> 128, bf16 MFMA
__global__ __launch_bounds__(256) void k_embed(
    const float* __restrict__ obs,
    const u16* __restrict__ pw0, const float* __restrict__ re_b0,
    const u16* __restrict__ pw1, const float* __restrict__ re_b1,
    const u16* __restrict__ pw2, const float* __restrict__ re_b2,
    u16* __restrict__ li_bf, float* __restrict__ runner_last)
{
    __shared__ __align__(16) u16 xr[32*40];      // stride 40 (80B)
    __shared__ __align__(16) u16 act1[32*136];   // stride 136 (272B)
    __shared__ __align__(16) u16 act2[32*136];
    __shared__ float bs0[128], bs1[128], bs2[128];

    int bt = blockIdx.x, tid = threadIdx.x;
    const float* row = obs + (size_t)bt*OBSD;

    for (int idx=tid; idx<1024; idx+=256){
        int r = idx>>5, k = idx&31;
        float v = 0.f;
        if (r < 30) v = (k<24) ? row[30 + r*24 + k] : row[760 + r*8 + (k-24)];
        xr[r*40 + k] = f2b(v);
    }
    if (tid < 128){ bs0[tid]=re_b0[tid]; bs1[tid]=re_b1[tid]; bs2[tid]=re_b2[tid]; }
    __syncthreads();

    int lane = tid & 63, wv = tid >> 6;
    int lr = lane & 15, lk = lane >> 4;
    f32x4 zero = {0.f,0.f,0.f,0.f};

    // ---- layer 0 (K=32) ----
    f32x4 d[2][2];
    {
        bf16x8 a0 = *(const bf16x8*)(xr + lr*40      + lk*8);
        bf16x8 a1 = *(const bf16x8*)(xr + (16+lr)*40 + lk*8);
        #pragma unroll
        for (int ns=0; ns<2; ns++){
            int n = 2*wv + ns;
            bf16x8 b = *(const bf16x8*)(pw0 + (size_t)(n*64 + lane)*8);
            d[0][ns] = MFMA(a0, b, zero);
            d[1][ns] = MFMA(a1, b, zero);
        }
    }
    #pragma unroll
    for (int m=0;m<2;m++)
        #pragma unroll
        for (int ns=0;ns<2;ns++){
            int col = (2*wv+ns)*16 + lr;
            float bias = bs0[col];
            #pragma unroll
            for (int r=0;r<4;r++){
                int rw = m*16 + lk*4 + r;
                act1[rw*136 + col] = f2b(fmaxf(d[m][ns][r] + bias, 0.f));
            }
        }
    __syncthreads();

    // ---- layer 1 (K=128) ----
    #pragma unroll
    for (int m=0;m<2;m++)
        #pragma unroll
        for (int ns=0;ns<2;ns++) d[m][ns] = zero;
    #pragma unroll
    for (int kc=0; kc<4; kc++){
        bf16x8 a0 = *(const bf16x8*)(act1 + lr*136      + kc*32 + lk*8);
        bf16x8 a1 = *(const bf16x8*)(act1 + (16+lr)*136 + kc*32 + lk*8);
        #pragma unroll
        for (int ns=0; ns<2; ns++){
            int n = 2*wv + ns;
            bf16x8 b = *(const bf16x8*)(pw1 + (size_t)((n*4 + kc)*64 + lane)*8);
            d[0][ns] = MFMA(a0, b, d[0][ns]);
            d[1][ns] = MFMA(a1, b, d[1][ns]);
        }
    }
    #pragma unroll
    for (int m=0;m<2;m++)
        #pragma unroll
        for (int ns=0;ns<2;ns++){
            int col = (2*wv+ns)*16 + lr;
            float bias = bs1[col];
            #pragma unroll
            for (int r=0;r<4;r++){
                int rw = m*16 + lk*4 + r;
                act2[rw*136 + col] = f2b(fmaxf(d[m][ns][r] + bias, 0.f));
            }
        }
    __syncthreads();

    // ---- layer 2 (K=128, no relu) + reductions ----
    #pragma unroll
    for (int m=0;m<2;m++)
        #pragma unroll
        for (int ns=0;ns<2;ns++) d[m][ns] = zero;
    #pragma unroll
    for (int kc=0; kc<4; kc++){
        bf16x8 a0 = *(const bf16x8*)(act2 + lr*136      + kc*32 + lk*8);
        bf16x8 a1 = *(const bf16x8*)(act2 + (16+lr)*136 + kc*32 + lk*8);
        #pragma unroll
        for (int ns=0; ns<2; ns++){
            int n = 2*wv + ns;
            bf16x8 b = *(const bf16x8*)(pw2 + (size_t)((n*4 + kc)*64 + lane)*8);
            d[0][ns] = MFMA(a0, b, d[0][ns]);
            d[1][ns] = MFMA(a1, b, d[1][ns]);
        }
    }

    u16* li = li_bf + (size_t)bt*LIN;
    bool last = ((bt & 63) == 63);
    int bb = bt >> 6;
    #pragma unroll
    for (int ns=0; ns<2; ns++){
        int col = (2*wv+ns)*16 + lr;
        float bias = bs2[col];
        float sum = 0.f, mx = -3.4e38f;
        float vals[2][4];
        #pragma unroll
        for (int m=0;m<2;m++)
            #pragma unroll
            for (int r=0;r<4;r++){
                int rw = m*16 + lk*4 + r;
                float v = d[m][ns][r] + bias;
                vals[m][r] = v;
                bool ok = rw < 30;
                sum += ok ? v : 0.f;
                mx = fmaxf(mx, ok ? v : -3.4e38f);
            }
        sum += __shfl_xor(sum, 16); sum += __shfl_xor(sum, 32);
        mx = fmaxf(mx, __shfl_xor(mx, 16)); mx = fmaxf(mx, __shfl_xor(mx, 32));
        if (lane < 16){
            li[128 + col] = f2b(sum * (1.0f/30.0f));
            li[256 + col] = f2b(mx);
        }
        if (last){
            #pragma unroll
            for (int m=0;m<2;m++)
                #pragma unroll
                for (int r=0;r<4;r++){
                    int rw = m*16 + lk*4 + r;
                    if (rw < 30) runner_last[(size_t)bb*3840 + rw*128 + col] = vals[m][r];
                }
        }
    }
}

// ---------------- market embed (MFMA), 32 rows per block ----------------
__global__ __launch_bounds__(256) void k_market(
    const float* __restrict__ obs,
    const u16* __restrict__ pm0, const float* __restrict__ me_b0,
    const u16* __restrict__ pm1, const float* __restrict__ me_b1,
    const u16* __restrict__ pm2, const float* __restrict__ me_b2,
    u16* __restrict__ li_bf)
{
    __shared__ __align__(16) u16 xm[32*72];      // K padded to 64, stride 72
    __shared__ __align__(16) u16 ma1[32*136];
    __shared__ __align__(16) u16 ma2[32*136];
    __shared__ float bs0[128], bs1[128], bs2[128];

    int bt0 = blockIdx.x*32, tid = threadIdx.x;
    for (int idx=tid; idx<2048; idx+=256){
        int r = idx>>6, k = idx&63;
        const float* row = obs + (size_t)(bt0+r)*OBSD;
        float v = 0.f;
        if (k < 30) v = row[k];
        else if (k < 40) v = row[720 + k];
        xm[r*72 + k] = f2b(v);
    }
    if (tid < 128){ bs0[tid]=me_b0[tid]; bs1[tid]=me_b1[tid]; bs2[tid]=me_b2[tid]; }
    __syncthreads();

    int lane = tid & 63, wv = tid >> 6;
    int lr = lane & 15, lk = lane >> 4;
    f32x4 zero = {0.f,0.f,0.f,0.f};
    f32x4 d[2][2];

    // layer 0 (Kpad=64)
    #pragma unroll
    for (int m=0;m<2;m++)
        #pragma unroll
        for (int ns=0;ns<2;ns++) d[m][ns] = zero;
    #pragma unroll
    for (int kc=0; kc<2; kc++){
        bf16x8 a0 = *(const bf16x8*)(xm + lr*72      + kc*32 + lk*8);
        bf16x8 a1 = *(const bf16x8*)(xm + (16+lr)*72 + kc*32 + lk*8);
        #pragma unroll
        for (int ns=0; ns<2; ns++){
            int n = 2*wv + ns;
            bf16x8 b = *(const bf16x8*)(pm0 + (size_t)((n*2 + kc)*64 + lane)*8);
            d[0][ns] = MFMA(a0, b, d[0][ns]);
            d[1][ns] = MFMA(a1, b, d[1][ns]);
        }
    }
    #pragma unroll
    for (int m=0;m<2;m++)
        #pragma unroll
        for (int ns=0;ns<2;ns++){
            int col = (2*wv+ns)*16 + lr;
            float bias = bs0[col];
            #pragma unroll
            for (int r=0;r<4;r++){
                int rw = m*16 + lk*4 + r;
                ma1[rw*136 + col] = f2b(fmaxf(d[m][ns][r] + bias, 0.f));
            }
        }
    __syncthreads();

    // layer 1
    #pragma unroll
    for (int m=0;m<2;m++)
        #pragma unroll
        for (int ns=0;ns<2;ns++) d[m][ns] = zero;
    #pragma unroll
    for (int kc=0; kc<4; kc++){
        bf16x8 a0 = *(const bf16x8*)(ma1 + lr*136      + kc*32 + lk*8);
        bf16x8 a1 = *(const bf16x8*)(ma1 + (16+lr)*136 + kc*32 + lk*8);
        #pragma unroll
        for (int ns=0; ns<2; ns++){
            int n = 2*wv + ns;
            bf16x8 b = *(const bf16x8*)(pm1 + (size_t)((n*4 + kc)*64 + lane)*8);
            d[0][ns] = MFMA(a0, b, d[0][ns]);
            d[1][ns] = MFMA(a1, b, d[1][ns]);
        }
    }
    #pragma unroll
    for (int m=0;m<2;m++)
        #pragma unroll
        for (int ns=0;ns<2;ns++){
            int col = (2*wv+ns)*16 + lr;
            float bias = bs1[col];
            #pragma unroll
            for (int r=0;r<4;r++){
                int rw = m*16 + lk*4 + r;
                ma2[rw*136 + col] = f2b(fmaxf(d[m][ns][r] + bias, 0.f));
            }
        }
    __syncthreads();

    // layer 2 (no relu) -> li[0..127]
    #pragma unroll
    for (int m=0;m<2;m++)
        #pragma unroll
        for (int ns=0;ns<2;ns++) d[m][ns] = zero;
    #pragma unroll
    for (int kc=0; kc<4; kc++){
        bf16x8 a0 = *(const bf16x8*)(ma2 + lr*136      + kc*32 + lk*8);
        bf16x8 a1 = *(const bf16x8*)(ma2 + (16+lr)*136 + kc*32 + lk*8);
        #pragma unroll
        for (int ns=0; ns<2; ns++){
            int n = 2*wv + ns;
            bf16x8 b = *(const bf16x8*)(pm2 + (size_t)((n*4 + kc)*64 + lane)*8);
            d[0][ns] = MFMA(a0, b, d[0][ns]);
            d[1][ns] = MFMA(a1, b, d[1][ns]);
        }
    }
    #pragma unroll
    for (int m=0;m<2;m++)
        #pragma unroll
        for (int ns=0;ns<2;ns++){
            int col = (2*wv+ns)*16 + lr;
            float bias = bs2[col];
            #pragma unroll
            for (int r=0;r<4;r++){
                int rw = m*16 + lk*4 + r;
                li_bf[(size_t)(bt0+rw)*LIN + col] = f2b(d[m][ns][r] + bias);
            }
        }
}

// ---------------- xW precompute (MFMA): gates for all (b,t) ----------------
// xw4[(row*256 + j)*4 + g] = (lstm_in[row] @ W_ih.T + b_ih)[g*256+j]
__global__ __launch_bounds__(256) void k_xw(
    const u16* __restrict__ A, const u16* __restrict__ pwih,
    const float* __restrict__ b_ih, float* __restrict__ xw4)
{
    int tid = threadIdx.x;
    int lane = tid & 63, wv = tid >> 6;
    int lr = lane & 15, lk = lane >> 4;
    int m0 = blockIdx.x * 16;
    int n0 = wv * 16;

    bf16x8 a[12];
    #pragma unroll
    for (int kc=0; kc<12; kc++)
        a[kc] = *(const bf16x8*)(A + (size_t)(m0+lr)*384 + kc*32 + lk*8);

    f32x4 acc[16];
    #pragma unroll
    for (int i=0;i<16;i++){
        float b = b_ih[(n0+i)*16 + lr];
        acc[i] = (f32x4){b,b,b,b};
    }

    for (int kc=0; kc<12; kc++){
        #pragma unroll
        for (int i=0;i<16;i++){
            bf16x8 b = *(const bf16x8*)(pwih + (size_t)(((n0+i)*12 + kc)*64 + lane)*8);
            acc[i] = MFMA(a[kc], b, acc[i]);
        }
    }

    #pragma unroll
    for (int i=0;i<16;i++){
        int col = (n0+i)*16 + lr;
        int g = col >> 8, jj = col & 255;
        #pragma unroll
        for (int r=0;r<4;r++){
            int row = m0 + lk*4 + r;
            xw4[((size_t)row*256 + jj)*4 + g] = acc[i][r];
        }
    }
}

// ---------------- LSTM step ----------------
// block: 16 batches x 16 cols; grid 256
__global__ __launch_bounds__(256) void k_lstm_step(
    const float* __restrict__ xw4, const float* __restrict__ W4,
    const float* __restrict__ W_dt, const float* __restrict__ obs,
    const float* __restrict__ h_in, float* __restrict__ h_out,
    float* __restrict__ c, int t)
{
    __shared__ float hl[16*260];
    int tid = threadIdx.x;
    int bg = blockIdx.x >> 4, jg = blockIdx.x & 15;
    for (int idx=tid; idx<4096; idx+=256){
        int r = idx>>8, k = idx&255;
        hl[r*260 + k] = h_in[(size_t)(bg*16 + r)*256 + k];
    }
    __syncthreads();

    int bl = tid >> 4, jl = tid & 15;
    int b = bg*16 + bl, j = jg*16 + jl;
    float4 acc = *(const float4*)(xw4 + ((size_t)(b*64 + t)*256 + j)*4);
    const float* hr = hl + bl*260;
    #pragma unroll 8
    for (int k=0;k<256;k++){
        float hv = hr[k];
        float4 w = *(const float4*)(W4 + ((size_t)k*256 + j)*4);
        acc.x = fmaf(hv, w.x, acc.x);
        acc.y = fmaf(hv, w.y, acc.y);
        acc.z = fmaf(hv, w.z, acc.z);
        acc.w = fmaf(hv, w.w, acc.w);
    }
    float d  = obs[(size_t)(b*64 + t)*OBSD + TDI];
    float fi = sigm(acc.x);
    float ff = sigm(acc.y + W_dt[j]*d);
    float gg = tanhf(acc.z);
    float oo = sigm(acc.w);
    int ci = b*256 + j;
    float cn = fmaf(ff, c[ci], fi*gg);
    c[ci] = cn;
    h_out[ci] = oo * tanhf(cn);
}

// ---------------- heads (fp32, unchanged) ----------------
__device__ __forceinline__ void dense30(
    const float* in, int istride,
    const float* __restrict__ W, int wstride, int K,
    const float* __restrict__ bias, const float* extra,
    float* outp, int ostride, bool relu, int j, int rh)
{
    float acc[15];
    #pragma unroll
    for (int i=0;i<15;i++) acc[i]=0.f;
    const float* w = W + j*wstride;
    for (int k=0;k<K;k+=4){
        float4 wv = *(const float4*)(w+k);
        #pragma unroll
        for (int i=0;i<15;i++){
            float4 xv = *(const float4*)(in + (rh+2*i)*istride + k);
            acc[i] = fmaf(wv.x,xv.x,acc[i]);
            acc[i] = fmaf(wv.y,xv.y,acc[i]);
            acc[i] = fmaf(wv.z,xv.z,acc[i]);
            acc[i] = fmaf(wv.w,xv.w,acc[i]);
        }
    }
    float bb = bias[j] + (extra ? extra[j] : 0.f);
    #pragma unroll
    for (int i=0;i<15;i++){
        float v = acc[i]+bb;
        outp[(rh+2*i)*ostride+j] = relu ? fmaxf(v,0.f) : v;
    }
}

__device__ __forceinline__ float dense1(
    const float* in, const float* __restrict__ W,
    const float* __restrict__ bias, int K, int j)
{
    const float* w = W + j*K;
    float s = 0.f;
    for (int k=0;k<K;k+=4){
        float4 wv = *(const float4*)(w+k);
        float4 xv = *(const float4*)(in+k);
        s = fmaf(wv.x,xv.x,s); s = fmaf(wv.y,xv.y,s);
        s = fmaf(wv.z,xv.z,s); s = fmaf(wv.w,xv.w,s);
    }
    return s + bias[j];
}

__global__ __launch_bounds__(256) void k_heads(
    const float* __restrict__ h, const float* __restrict__ cbuf,
    const float* __restrict__ rl,
    const float* __restrict__ a_w0, const float* __restrict__ a_b0,
    const float* __restrict__ a_w1, const float* __restrict__ a_b1,
    const float* __restrict__ c_w0, const float* __restrict__ c_b0,
    const float* __restrict__ c_w1, const float* __restrict__ c_b1,
    const float* __restrict__ log_std,
    float* __restrict__ out)
{
    __shared__ __align__(16) float hv[LH];
    __shared__ __align__(16) float rls[NR][HD];
    __shared__ __align__(16) float hid[NR][HD];
    __shared__ __align__(16) float dot2[HD];
    __shared__ __align__(16) float red[128];

    int b = blockIdx.x, tid = threadIdx.x;
    hv[tid] = h[b*LH + tid];
    for (int idx=tid; idx<NR*HD; idx+=256) rls[idx>>7][idx&127] = rl[(size_t)b*NR*HD + idx];
    __syncthreads();

    if (tid < 128){
        const float* w = a_w0 + tid*LIN + HD;
        float s = 0.f;
        for (int k=0;k<LH;k+=4){
            float4 wv = *(const float4*)(w+k);
            s = fmaf(wv.x,hv[k],s); s = fmaf(wv.y,hv[k+1],s);
            s = fmaf(wv.z,hv[k+2],s); s = fmaf(wv.w,hv[k+3],s);
        }
        dot2[tid] = s;
    }
    __syncthreads();

    int j = tid & 127, rh = tid >> 7;
    dense30(&rls[0][0], HD, a_w0, LIN, HD, a_b0, dot2, &hid[0][0], HD, true, j, rh);
    __syncthreads();

    if (tid < 60){
        int r = tid >> 1, o = tid & 1;
        const float* w = a_w1 + o*HD;
        float s = a_b1[o];
        for (int k=0;k<HD;k++) s = fmaf(hid[r][k], w[k], s);
        out[AM_OFF + b*60 + tid] = s;
        out[ALS_OFF + b*60 + tid] = log_std[tid];
    }

    float term = 0.f;
    if (tid < 128) term = fmaxf(dense1(hv, c_w0, c_b0, LH, tid), 0.f) * c_w1[tid];
    if (tid < 128) red[tid] = term;
    __syncthreads();
    for (int s2=64; s2>0; s2>>=1){
        if (tid < s2) red[tid] += red[tid+s2];
        __syncthreads();
    }
    if (tid == 0) out[V_OFF + b] = red[0] + c_b1[0];

    out[H_OFF + b*LH + tid] = hv[tid];
    out[C_OFF + b*LH + tid] = cbuf[b*LH + tid];
}

extern "C" void kernel_launch(void* const* d_in, const int* in_sizes, int n_in,
                              void* d_out, int out_size, void* d_ws, size_t ws_size,
                              hipStream_t stream)
{
    const float* obs   = (const float*)d_in[0];
    const float* re_w0 = (const float*)d_in[1];
    const float* re_b0 = (const float*)d_in[2];
    const float* re_w1 = (const float*)d_in[3];
    const float* re_b1 = (const float*)d_in[4];
    const float* re_w2 = (const float*)d_in[5];
    const float* re_b2 = (const float*)d_in[6];
    const float* me_w0 = (const float*)d_in[7];
    const float* me_b0 = (const float*)d_in[8];
    const float* me_w1 = (const float*)d_in[9];
    const float* me_b1 = (const float*)d_in[10];
    const float* me_w2 = (const float*)d_in[11];
    const float* me_b2 = (const float*)d_in[12];
    const float* W_ih  = (const float*)d_in[13];
    const float* b_ih  = (const float*)d_in[14];
    const float* W_hh  = (const float*)d_in[15];
    const float* W_dt  = (const float*)d_in[16];
    const float* a_w0  = (const float*)d_in[17];
    const float* a_b0  = (const float*)d_in[18];
    const float* a_w1  = (const float*)d_in[19];
    const float* a_b1  = (const float*)d_in[20];
    const float* c_w0  = (const float*)d_in[21];
    const float* c_b0  = (const float*)d_in[22];
    const float* c_w1  = (const float*)d_in[23];
    const float* c_b1  = (const float*)d_in[24];
    const float* lstd  = (const float*)d_in[25];
    float* out = (float*)d_out;

    float* ws = (float*)d_ws;
    size_t off = 0;
    float* xw4 = ws + off; off += (size_t)16384*1024;
    float* h0  = ws + off; off += (size_t)Bn*LH;
    float* h1  = ws + off; off += (size_t)Bn*LH;
    float* cb  = ws + off; off += (size_t)Bn*LH;
    float* rl  = ws + off; off += (size_t)Bn*NR*HD;
    float* W4  = ws + off; off += (size_t)LH*1024;

    u16* us = (u16*)(ws + off);
    size_t uo = 0;
    u16* li_bf = us + uo; uo += (size_t)16384*LIN;
    u16* pw0   = us + uo; uo += 128*32;
    u16* pw1   = us + uo; uo += 128*128;
    u16* pw2   = us + uo; uo += 128*128;
    u16* pm0   = us + uo; uo += 128*64;
    u16* pm1   = us + uo; uo += 128*128;
    u16* pm2   = us + uo; uo += 128*128;
    u16* pwih  = us + uo; uo += (size_t)1024*384;

    hipMemsetAsync(h0, 0, (size_t)Bn*LH*sizeof(float), stream);
    hipMemsetAsync(cb, 0, (size_t)Bn*LH*sizeof(float), stream);

    k_pack<<<16,   256, 0, stream>>>(re_w0, pw0, 128, 32, 32);
    k_pack<<<64,   256, 0, stream>>>(re_w1, pw1, 128, 128, 128);
    k_pack<<<64,   256, 0, stream>>>(re_w2, pw2, 128, 128, 128);
    k_pack<<<32,   256, 0, stream>>>(me_w0, pm0, 128, 40, 64);
    k_pack<<<64,   256, 0, stream>>>(me_w1, pm1, 128, 128, 128);
    k_pack<<<64,   256, 0, stream>>>(me_w2, pm2, 128, 128, 128);
    k_pack<<<1536, 256, 0, stream>>>(W_ih, pwih, 1024, 384, 384);
    k_packW4<<<256, 256, 0, stream>>>(W_hh, W4);

    k_embed<<<16384, 256, 0, stream>>>(obs, pw0, re_b0, pw1, re_b1, pw2, re_b2,
                                       li_bf, rl);
    k_market<<<512, 256, 0, stream>>>(obs, pm0, me_b0, pm1, me_b1, pm2, me_b2,
                                      li_bf);
    k_xw<<<1024, 256, 0, stream>>>(li_bf, pwih, b_ih, xw4);

    for (int t=0; t<Tn; t++){
        const float* hi = (t & 1) ? h1 : h0;
        float*       ho = (t & 1) ? h0 : h1;
        k_lstm_step<<<256, 256, 0, stream>>>(xw4, W4, W_dt, obs, hi, ho, cb, t);
    }

    k_heads<<<256, 256, 0, stream>>>(h0, cb, rl,
        a_w0, a_b0, a_w1, a_b1, c_w0, c_b0, c_w1, c_b1, lstd, out);
}

// Round 3
// 799.314 us; speedup vs baseline: 3.0278x; 1.1579x over previous
//
#include <hip/hip_runtime.h>
#include <hip/hip_bf16.h>
#include <math.h>

#define Bn 256
#define Tn 64
#define OBSD 1000
#define NR 30
#define HD 128
#define LH 256
#define LIN 384
#define TDI 26

#define AM_OFF 0
#define ALS_OFF 15360
#define V_OFF 30720
#define H_OFF 30976
#define C_OFF 96512

typedef unsigned short u16;
typedef short bf16x8 __attribute__((ext_vector_type(8)));
typedef float f32x4 __attribute__((ext_vector_type(4)));

__device__ __forceinline__ float sigm(float x){ return 1.f/(1.f+__expf(-x)); }
__device__ __forceinline__ float tanhfast(float x){
    float ax = fabsf(x);
    float e = __expf(2.f*ax);
    float t = 1.f - 2.f/(e+1.f);
    return copysignf(t, x);
}

__device__ __forceinline__ u16 f2b(float f){
    union { __hip_bfloat16 h; u16 u; } cv;
    cv.h = __float2bfloat16(f);
    return cv.u;
}

#define MFMA(a,b,c) __builtin_amdgcn_mfma_f32_16x16x32_bf16(a,b,c,0,0,0)

// ---------------- packing kernels ----------------
// pack W[N][K] (fp32, row-major [out][in]) into bf16 MFMA B-fragment order:
// frag chunk (ntile, kc): lane l holds W[ntile*16 + (l&15)][kc*32 + (l>>4)*8 + e]
__global__ void k_pack(const float* __restrict__ src, u16* __restrict__ dst,
                       int N, int K, int Kpad)
{
    int t = blockIdx.x*256 + threadIdx.x;
    if (t >= N*Kpad) return;
    int j = t / Kpad, k = t - j*Kpad;
    float v = (k < K) ? src[j*K + k] : 0.f;
    int ntile = j>>4, jr = j&15, kc = k>>5, ko = k&31;
    int lane = ((ko>>3)<<4) | jr, elem = ko&7;
    int KC = Kpad>>5;
    dst[(size_t)(((ntile*KC + kc)*64) + lane)*8 + elem] = f2b(v);
}

// gate-interleaved pack for W_ih / W_hh (N=1024 rows, 4 gates of 256):
// packed col c = nt*16 + jr, nt = jg*4 + g  <->  src row = g*256 + jg*16 + jr
__global__ void k_pack_gi(const float* __restrict__ src, u16* __restrict__ dst, int K)
{
    int KC = K >> 5;
    int t = blockIdx.x*256 + threadIdx.x;
    if (t >= 1024*K) return;
    int n = t / K, k = t - n*K;
    int nt = n>>4, jr = n&15;
    int jg = nt>>2, g = nt&3;
    float v = src[(size_t)(g*256 + jg*16 + jr)*K + k];
    int kc = k>>5, ko = k&31;
    int lane = ((ko>>3)<<4) | jr, e = ko&7;
    dst[(size_t)(((nt*KC + kc)*64) + lane)*8 + e] = f2b(v);
}

// dtv[t*256 + b] = obs[(b*64+t)*OBSD + TDI]
__global__ void k_dtv(const float* __restrict__ obs, float* __restrict__ dtv)
{
    int idx = blockIdx.x*256 + threadIdx.x;   // 16384
    int b = idx >> 6, t = idx & 63;
    dtv[t*256 + b] = obs[(size_t)idx*OBSD + TDI];
}

// ---------------- runner embed (MFMA) ----------------
__global__ __launch_bounds__(256) void k_embed(
    const float* __restrict__ obs,
    const u16* __restrict__ pw0, const float* __restrict__ re_b0,
    const u16* __restrict__ pw1, const float* __restrict__ re_b1,
    const u16* __restrict__ pw2, const float* __restrict__ re_b2,
    u16* __restrict__ li_bf, float* __restrict__ runner_last)
{
    __shared__ __align__(16) u16 xr[32*40];
    __shared__ __align__(16) u16 act1[32*136];
    __shared__ __align__(16) u16 act2[32*136];
    __shared__ float bs0[128], bs1[128], bs2[128];

    int bt = blockIdx.x, tid = threadIdx.x;
    const float* row = obs + (size_t)bt*OBSD;

    for (int idx=tid; idx<1024; idx+=256){
        int r = idx>>5, k = idx&31;
        float v = 0.f;
        if (r < 30) v = (k<24) ? row[30 + r*24 + k] : row[760 + r*8 + (k-24)];
        xr[r*40 + k] = f2b(v);
    }
    if (tid < 128){ bs0[tid]=re_b0[tid]; bs1[tid]=re_b1[tid]; bs2[tid]=re_b2[tid]; }
    __syncthreads();

    int lane = tid & 63, wv = tid >> 6;
    int lr = lane & 15, lk = lane >> 4;
    f32x4 zero = {0.f,0.f,0.f,0.f};

    f32x4 d[2][2];
    {
        bf16x8 a0 = *(const bf16x8*)(xr + lr*40      + lk*8);
        bf16x8 a1 = *(const bf16x8*)(xr + (16+lr)*40 + lk*8);
        #pragma unroll
        for (int ns=0; ns<2; ns++){
            int n = 2*wv + ns;
            bf16x8 b = *(const bf16x8*)(pw0 + (size_t)(n*64 + lane)*8);
            d[0][ns] = MFMA(a0, b, zero);
            d[1][ns] = MFMA(a1, b, zero);
        }
    }
    #pragma unroll
    for (int m=0;m<2;m++)
        #pragma unroll
        for (int ns=0;ns<2;ns++){
            int col = (2*wv+ns)*16 + lr;
            float bias = bs0[col];
            #pragma unroll
            for (int r=0;r<4;r++){
                int rw = m*16 + lk*4 + r;
                act1[rw*136 + col] = f2b(fmaxf(d[m][ns][r] + bias, 0.f));
            }
        }
    __syncthreads();

    #pragma unroll
    for (int m=0;m<2;m++)
        #pragma unroll
        for (int ns=0;ns<2;ns++) d[m][ns] = zero;
    #pragma unroll
    for (int kc=0; kc<4; kc++){
        bf16x8 a0 = *(const bf16x8*)(act1 + lr*136      + kc*32 + lk*8);
        bf16x8 a1 = *(const bf16x8*)(act1 + (16+lr)*136 + kc*32 + lk*8);
        #pragma unroll
        for (int ns=0; ns<2; ns++){
            int n = 2*wv + ns;
            bf16x8 b = *(const bf16x8*)(pw1 + (size_t)((n*4 + kc)*64 + lane)*8);
            d[0][ns] = MFMA(a0, b, d[0][ns]);
            d[1][ns] = MFMA(a1, b, d[1][ns]);
        }
    }
    #pragma unroll
    for (int m=0;m<2;m++)
        #pragma unroll
        for (int ns=0;ns<2;ns++){
            int col = (2*wv+ns)*16 + lr;
            float bias = bs1[col];
            #pragma unroll
            for (int r=0;r<4;r++){
                int rw = m*16 + lk*4 + r;
                act2[rw*136 + col] = f2b(fmaxf(d[m][ns][r] + bias, 0.f));
            }
        }
    __syncthreads();

    #pragma unroll
    for (int m=0;m<2;m++)
        #pragma unroll
        for (int ns=0;ns<2;ns++) d[m][ns] = zero;
    #pragma unroll
    for (int kc=0; kc<4; kc++){
        bf16x8 a0 = *(const bf16x8*)(act2 + lr*136      + kc*32 + lk*8);
        bf16x8 a1 = *(const bf16x8*)(act2 + (16+lr)*136 + kc*32 + lk*8);
        #pragma unroll
        for (int ns=0; ns<2; ns++){
            int n = 2*wv + ns;
            bf16x8 b = *(const bf16x8*)(pw2 + (size_t)((n*4 + kc)*64 + lane)*8);
            d[0][ns] = MFMA(a0, b, d[0][ns]);
            d[1][ns] = MFMA(a1, b, d[1][ns]);
        }
    }

    u16* li = li_bf + (size_t)bt*LIN;
    bool last = ((bt & 63) == 63);
    int bb = bt >> 6;
    #pragma unroll
    for (int ns=0; ns<2; ns++){
        int col = (2*wv+ns)*16 + lr;
        float bias = bs2[col];
        float sum = 0.f, mx = -3.4e38f;
        float vals[2][4];
        #pragma unroll
        for (int m=0;m<2;m++)
            #pragma unroll
            for (int r=0;r<4;r++){
                int rw = m*16 + lk*4 + r;
                float v = d[m][ns][r] + bias;
                vals[m][r] = v;
                bool ok = rw < 30;
                sum += ok ? v : 0.f;
                mx = fmaxf(mx, ok ? v : -3.4e38f);
            }
        sum += __shfl_xor(sum, 16); sum += __shfl_xor(sum, 32);
        mx = fmaxf(mx, __shfl_xor(mx, 16)); mx = fmaxf(mx, __shfl_xor(mx, 32));
        if (lane < 16){
            li[128 + col] = f2b(sum * (1.0f/30.0f));
            li[256 + col] = f2b(mx);
        }
        if (last){
            #pragma unroll
            for (int m=0;m<2;m++)
                #pragma unroll
                for (int r=0;r<4;r++){
                    int rw = m*16 + lk*4 + r;
                    if (rw < 30) runner_last[(size_t)bb*3840 + rw*128 + col] = vals[m][r];
                }
        }
    }
}

// ---------------- market embed (MFMA), 32 rows per block ----------------
__global__ __launch_bounds__(256) void k_market(
    const float* __restrict__ obs,
    const u16* __restrict__ pm0, const float* __restrict__ me_b0,
    const u16* __restrict__ pm1, const float* __restrict__ me_b1,
    const u16* __restrict__ pm2, const float* __restrict__ me_b2,
    u16* __restrict__ li_bf)
{
    __shared__ __align__(16) u16 xm[32*72];
    __shared__ __align__(16) u16 ma1[32*136];
    __shared__ __align__(16) u16 ma2[32*136];
    __shared__ float bs0[128], bs1[128], bs2[128];

    int bt0 = blockIdx.x*32, tid = threadIdx.x;
    for (int idx=tid; idx<2048; idx+=256){
        int r = idx>>6, k = idx&63;
        const float* row = obs + (size_t)(bt0+r)*OBSD;
        float v = 0.f;
        if (k < 30) v = row[k];
        else if (k < 40) v = row[720 + k];
        xm[r*72 + k] = f2b(v);
    }
    if (tid < 128){ bs0[tid]=me_b0[tid]; bs1[tid]=me_b1[tid]; bs2[tid]=me_b2[tid]; }
    __syncthreads();

    int lane = tid & 63, wv = tid >> 6;
    int lr = lane & 15, lk = lane >> 4;
    f32x4 zero = {0.f,0.f,0.f,0.f};
    f32x4 d[2][2];

    #pragma unroll
    for (int m=0;m<2;m++)
        #pragma unroll
        for (int ns=0;ns<2;ns++) d[m][ns] = zero;
    #pragma unroll
    for (int kc=0; kc<2; kc++){
        bf16x8 a0 = *(const bf16x8*)(xm + lr*72      + kc*32 + lk*8);
        bf16x8 a1 = *(const bf16x8*)(xm + (16+lr)*72 + kc*32 + lk*8);
        #pragma unroll
        for (int ns=0; ns<2; ns++){
            int n = 2*wv + ns;
            bf16x8 b = *(const bf16x8*)(pm0 + (size_t)((n*2 + kc)*64 + lane)*8);
            d[0][ns] = MFMA(a0, b, d[0][ns]);
            d[1][ns] = MFMA(a1, b, d[1][ns]);
        }
    }
    #pragma unroll
    for (int m=0;m<2;m++)
        #pragma unroll
        for (int ns=0;ns<2;ns++){
            int col = (2*wv+ns)*16 + lr;
            float bias = bs0[col];
            #pragma unroll
            for (int r=0;r<4;r++){
                int rw = m*16 + lk*4 + r;
                ma1[rw*136 + col] = f2b(fmaxf(d[m][ns][r] + bias, 0.f));
            }
        }
    __syncthreads();

    #pragma unroll
    for (int m=0;m<2;m++)
        #pragma unroll
        for (int ns=0;ns<2;ns++) d[m][ns] = zero;
    #pragma unroll
    for (int kc=0; kc<4; kc++){
        bf16x8 a0 = *(const bf16x8*)(ma1 + lr*136      + kc*32 + lk*8);
        bf16x8 a1 = *(const bf16x8*)(ma1 + (16+lr)*136 + kc*32 + lk*8);
        #pragma unroll
        for (int ns=0; ns<2; ns++){
            int n = 2*wv + ns;
            bf16x8 b = *(const bf16x8*)(pm1 + (size_t)((n*4 + kc)*64 + lane)*8);
            d[0][ns] = MFMA(a0, b, d[0][ns]);
            d[1][ns] = MFMA(a1, b, d[1][ns]);
        }
    }
    #pragma unroll
    for (int m=0;m<2;m++)
        #pragma unroll
        for (int ns=0;ns<2;ns++){
            int col = (2*wv+ns)*16 + lr;
            float bias = bs1[col];
            #pragma unroll
            for (int r=0;r<4;r++){
                int rw = m*16 + lk*4 + r;
                ma2[rw*136 + col] = f2b(fmaxf(d[m][ns][r] + bias, 0.f));
            }
        }
    __syncthreads();

    #pragma unroll
    for (int m=0;m<2;m++)
        #pragma unroll
        for (int ns=0;ns<2;ns++) d[m][ns] = zero;
    #pragma unroll
    for (int kc=0; kc<4; kc++){
        bf16x8 a0 = *(const bf16x8*)(ma2 + lr*136      + kc*32 + lk*8);
        bf16x8 a1 = *(const bf16x8*)(ma2 + (16+lr)*136 + kc*32 + lk*8);
        #pragma unroll
        for (int ns=0; ns<2; ns++){
            int n = 2*wv + ns;
            bf16x8 b = *(const bf16x8*)(pm2 + (size_t)((n*4 + kc)*64 + lane)*8);
            d[0][ns] = MFMA(a0, b, d[0][ns]);
            d[1][ns] = MFMA(a1, b, d[1][ns]);
        }
    }
    #pragma unroll
    for (int m=0;m<2;m++)
        #pragma unroll
        for (int ns=0;ns<2;ns++){
            int col = (2*wv+ns)*16 + lr;
            float bias = bs2[col];
            #pragma unroll
            for (int r=0;r<4;r++){
                int rw = m*16 + lk*4 + r;
                li_bf[(size_t)(bt0+rw)*LIN + col] = f2b(d[m][ns][r] + bias);
            }
        }
}

// ---------------- xW precompute (MFMA) ----------------
// xw[row][g*256 + jg*16 + jl] = (lstm_in[row] @ W_ih.T + b_ih)[g*256+jg*16+jl]
// wave: 32 rows, loop over jg; W_ih packed gate-interleaved (nt = jg*4+g)
__global__ __launch_bounds__(256) void k_xw(
    const u16* __restrict__ A, const u16* __restrict__ pwih,
    const float* __restrict__ b_ih, float* __restrict__ xw)
{
    int tid = threadIdx.x;
    int lane = tid & 63, wv = tid >> 6;
    int lr = lane & 15, lk = lane >> 4;
    int r0 = (blockIdx.x*4 + wv) * 32;

    bf16x8 a[2][12];
    #pragma unroll
    for (int m=0;m<2;m++)
        #pragma unroll
        for (int kc=0;kc<12;kc++)
            a[m][kc] = *(const bf16x8*)(A + (size_t)(r0+m*16+lr)*384 + kc*32 + lk*8);

    for (int jg=0; jg<16; jg++){
        f32x4 acc[2][4];
        #pragma unroll
        for (int g=0; g<4; g++){
            float bias = b_ih[g*256 + jg*16 + lr];
            f32x4 v = {bias,bias,bias,bias};
            acc[0][g]=v; acc[1][g]=v;
        }
        #pragma unroll
        for (int kc=0; kc<12; kc++){
            bf16x8 b0 = *(const bf16x8*)(pwih + (size_t)(((jg*4+0)*12+kc)*64+lane)*8);
            bf16x8 b1 = *(const bf16x8*)(pwih + (size_t)(((jg*4+1)*12+kc)*64+lane)*8);
            bf16x8 b2 = *(const bf16x8*)(pwih + (size_t)(((jg*4+2)*12+kc)*64+lane)*8);
            bf16x8 b3 = *(const bf16x8*)(pwih + (size_t)(((jg*4+3)*12+kc)*64+lane)*8);
            #pragma unroll
            for (int m=0;m<2;m++){
                acc[m][0] = MFMA(a[m][kc], b0, acc[m][0]);
                acc[m][1] = MFMA(a[m][kc], b1, acc[m][1]);
                acc[m][2] = MFMA(a[m][kc], b2, acc[m][2]);
                acc[m][3] = MFMA(a[m][kc], b3, acc[m][3]);
            }
        }
        #pragma unroll
        for (int m=0;m<2;m++)
            #pragma unroll
            for (int g=0;g<4;g++)
                #pragma unroll
                for (int r=0;r<4;r++)
                    xw[(size_t)(r0+m*16+lk*4+r)*1024 + g*256 + jg*16 + lr] = acc[m][g][r];
    }
}

// ---------------- persistent LSTM over all 64 steps ----------------
// 64 blocks x 256 threads; wave owns [16 batches x (16 j x 4 gates)];
// W_hh B-frags in registers; h via bf16 double buffer; grid barrier per step.
__global__ __launch_bounds__(256,1) void k_lstm_all(
    const float* __restrict__ xw, const u16* __restrict__ pwhh,
    const float* __restrict__ W_dt, const float* __restrict__ dtv,
    u16* __restrict__ hb0, u16* __restrict__ hb1,
    float* __restrict__ hout, float* __restrict__ cout,
    unsigned int* __restrict__ bar)
{
    int tid = threadIdx.x;
    int lane = tid & 63, wv = tid >> 6;
    int lr = lane & 15, lk = lane >> 4;
    int jg = blockIdx.x & 15, bgq = blockIdx.x >> 4;
    int batchbase = (bgq*4 + wv)*16;
    int bout = batchbase + lk*4;
    int jcol = jg*16 + lr;

    bf16x8 bfr[4][8];
    #pragma unroll
    for (int g=0; g<4; g++)
        #pragma unroll
        for (int kc=0; kc<8; kc++)
            bfr[g][kc] = *(const bf16x8*)(pwhh + (size_t)(((jg*4+g)*8+kc)*64+lane)*8);

    float wdt = W_dt[jcol];
    float cst[4] = {0.f,0.f,0.f,0.f};

    float xwc[4][4], dtc[4];
    #pragma unroll
    for (int g=0; g<4; g++)
        #pragma unroll
        for (int r=0; r<4; r++)
            xwc[g][r] = xw[(size_t)(bout+r)*65536 + g*256 + jcol];
    #pragma unroll
    for (int r=0; r<4; r++) dtc[r] = dtv[bout + r];

    for (int t=0; t<64; t++){
        const u16* hr = (t&1) ? hb1 : hb0;
        u16*       hw = (t&1) ? hb0 : hb1;

        bf16x8 a[8];
        #pragma unroll
        for (int kc=0; kc<8; kc++)
            a[kc] = *(const bf16x8*)(hr + (size_t)(batchbase+lr)*256 + kc*32 + lk*8);

        f32x4 acc[4];
        #pragma unroll
        for (int g=0; g<4; g++){
            f32x4 v; v[0]=xwc[g][0]; v[1]=xwc[g][1]; v[2]=xwc[g][2]; v[3]=xwc[g][3];
            acc[g] = v;
        }
        float dcur[4];
        #pragma unroll
        for (int r=0;r<4;r++) dcur[r]=dtc[r];

        if (t < 63){
            #pragma unroll
            for (int g=0; g<4; g++)
                #pragma unroll
                for (int r=0; r<4; r++)
                    xwc[g][r] = xw[(size_t)(bout+r)*65536 + (size_t)(t+1)*1024 + g*256 + jcol];
            #pragma unroll
            for (int r=0;r<4;r++) dtc[r] = dtv[(t+1)*256 + bout + r];
        }

        #pragma unroll
        for (int kc=0; kc<8; kc++){
            acc[0] = MFMA(a[kc], bfr[0][kc], acc[0]);
            acc[1] = MFMA(a[kc], bfr[1][kc], acc[1]);
            acc[2] = MFMA(a[kc], bfr[2][kc], acc[2]);
            acc[3] = MFMA(a[kc], bfr[3][kc], acc[3]);
        }

        #pragma unroll
        for (int r=0; r<4; r++){
            float gi = sigm(acc[0][r]);
            float gf = sigm(acc[1][r] + wdt*dcur[r]);
            float gg = tanhfast(acc[2][r]);
            float go = sigm(acc[3][r]);
            float cn = fmaf(gf, cst[r], gi*gg);
            cst[r] = cn;
            float hv = go * tanhfast(cn);
            hw[(size_t)(bout+r)*256 + jcol] = f2b(hv);
            if (t == 63){
                hout[(size_t)(bout+r)*256 + jcol] = hv;
                cout[(size_t)(bout+r)*256 + jcol] = cn;
            }
        }

        if (t < 63){
            __syncthreads();
            if (tid == 0){
                __threadfence();
                __hip_atomic_fetch_add(bar, 1u, __ATOMIC_RELAXED, __HIP_MEMORY_SCOPE_AGENT);
                unsigned int tgt = 64u*(unsigned int)(t+1);
                while (__hip_atomic_load(bar, __ATOMIC_RELAXED, __HIP_MEMORY_SCOPE_AGENT) < tgt)
                    __builtin_amdgcn_s_sleep(2);
                __threadfence();
            }
            __syncthreads();
        }
    }
}

// ---------------- heads (fp32) ----------------
__device__ __forceinline__ void dense30(
    const float* in, int istride,
    const float* __restrict__ W, int wstride, int K,
    const float* __restrict__ bias, const float* extra,
    float* outp, int ostride, bool relu, int j, int rh)
{
    float acc[15];
    #pragma unroll
    for (int i=0;i<15;i++) acc[i]=0.f;
    const float* w = W + j*wstride;
    for (int k=0;k<K;k+=4){
        float4 wv = *(const float4*)(w+k);
        #pragma unroll
        for (int i=0;i<15;i++){
            float4 xv = *(const float4*)(in + (rh+2*i)*istride + k);
            acc[i] = fmaf(wv.x,xv.x,acc[i]);
            acc[i] = fmaf(wv.y,xv.y,acc[i]);
            acc[i] = fmaf(wv.z,xv.z,acc[i]);
            acc[i] = fmaf(wv.w,xv.w,acc[i]);
        }
    }
    float bb = bias[j] + (extra ? extra[j] : 0.f);
    #pragma unroll
    for (int i=0;i<15;i++){
        float v = acc[i]+bb;
        outp[(rh+2*i)*ostride+j] = relu ? fmaxf(v,0.f) : v;
    }
}

__device__ __forceinline__ float dense1(
    const float* in, const float* __restrict__ W,
    const float* __restrict__ bias, int K, int j)
{
    const float* w = W + j*K;
    float s = 0.f;
    for (int k=0;k<K;k+=4){
        float4 wv = *(const float4*)(w+k);
        float4 xv = *(const float4*)(in+k);
        s = fmaf(wv.x,xv.x,s); s = fmaf(wv.y,xv.y,s);
        s = fmaf(wv.z,xv.z,s); s = fmaf(wv.w,xv.w,s);
    }
    return s + bias[j];
}

__global__ __launch_bounds__(256) void k_heads(
    const float* __restrict__ h, const float* __restrict__ cbuf,
    const float* __restrict__ rl,
    const float* __restrict__ a_w0, const float* __restrict__ a_b0,
    const float* __restrict__ a_w1, const float* __restrict__ a_b1,
    const float* __restrict__ c_w0, const float* __restrict__ c_b0,
    const float* __restrict__ c_w1, const float* __restrict__ c_b1,
    const float* __restrict__ log_std,
    float* __restrict__ out)
{
    __shared__ __align__(16) float hv[LH];
    __shared__ __align__(16) float rls[NR][HD];
    __shared__ __align__(16) float hid[NR][HD];
    __shared__ __align__(16) float dot2[HD];
    __shared__ __align__(16) float red[128];

    int b = blockIdx.x, tid = threadIdx.x;
    hv[tid] = h[b*LH + tid];
    for (int idx=tid; idx<NR*HD; idx+=256) rls[idx>>7][idx&127] = rl[(size_t)b*NR*HD + idx];
    __syncthreads();

    if (tid < 128){
        const float* w = a_w0 + tid*LIN + HD;
        float s = 0.f;
        for (int k=0;k<LH;k+=4){
            float4 wv = *(const float4*)(w+k);
            s = fmaf(wv.x,hv[k],s); s = fmaf(wv.y,hv[k+1],s);
            s = fmaf(wv.z,hv[k+2],s); s = fmaf(wv.w,hv[k+3],s);
        }
        dot2[tid] = s;
    }
    __syncthreads();

    int j = tid & 127, rh = tid >> 7;
    dense30(&rls[0][0], HD, a_w0, LIN, HD, a_b0, dot2, &hid[0][0], HD, true, j, rh);
    __syncthreads();

    if (tid < 60){
        int r = tid >> 1, o = tid & 1;
        const float* w = a_w1 + o*HD;
        float s = a_b1[o];
        for (int k=0;k<HD;k++) s = fmaf(hid[r][k], w[k], s);
        out[AM_OFF + b*60 + tid] = s;
        out[ALS_OFF + b*60 + tid] = log_std[tid];
    }

    float term = 0.f;
    if (tid < 128) term = fmaxf(dense1(hv, c_w0, c_b0, LH, tid), 0.f) * c_w1[tid];
    if (tid < 128) red[tid] = term;
    __syncthreads();
    for (int s2=64; s2>0; s2>>=1){
        if (tid < s2) red[tid] += red[tid+s2];
        __syncthreads();
    }
    if (tid == 0) out[V_OFF + b] = red[0] + c_b1[0];

    out[H_OFF + b*LH + tid] = hv[tid];
    out[C_OFF + b*LH + tid] = cbuf[b*LH + tid];
}

extern "C" void kernel_launch(void* const* d_in, const int* in_sizes, int n_in,
                              void* d_out, int out_size, void* d_ws, size_t ws_size,
                              hipStream_t stream)
{
    const float* obs   = (const float*)d_in[0];
    const float* re_w0 = (const float*)d_in[1];
    const float* re_b0 = (const float*)d_in[2];
    const float* re_w1 = (const float*)d_in[3];
    const float* re_b1 = (const float*)d_in[4];
    const float* re_w2 = (const float*)d_in[5];
    const float* re_b2 = (const float*)d_in[6];
    const float* me_w0 = (const float*)d_in[7];
    const float* me_b0 = (const float*)d_in[8];
    const float* me_w1 = (const float*)d_in[9];
    const float* me_b1 = (const float*)d_in[10];
    const float* me_w2 = (const float*)d_in[11];
    const float* me_b2 = (const float*)d_in[12];
    const float* W_ih  = (const float*)d_in[13];
    const float* b_ih  = (const float*)d_in[14];
    const float* W_hh  = (const float*)d_in[15];
    const float* W_dt  = (const float*)d_in[16];
    const float* a_w0  = (const float*)d_in[17];
    const float* a_b0  = (const float*)d_in[18];
    const float* a_w1  = (const float*)d_in[19];
    const float* a_b1  = (const float*)d_in[20];
    const float* c_w0  = (const float*)d_in[21];
    const float* c_b0  = (const float*)d_in[22];
    const float* c_w1  = (const float*)d_in[23];
    const float* c_b1  = (const float*)d_in[24];
    const float* lstd  = (const float*)d_in[25];
    float* out = (float*)d_out;

    float* ws = (float*)d_ws;
    size_t off = 0;
    float* xw4  = ws + off; off += (size_t)16384*1024;
    float* hout = ws + off; off += (size_t)Bn*LH;
    float* cb   = ws + off; off += (size_t)Bn*LH;
    float* rl   = ws + off; off += (size_t)Bn*NR*HD;
    float* dtv  = ws + off; off += (size_t)16384;
    unsigned int* bar = (unsigned int*)(ws + off); off += 64;

    u16* us = (u16*)(ws + off);
    size_t uo = 0;
    u16* li_bf = us + uo; uo += (size_t)16384*LIN;
    u16* pw0   = us + uo; uo += 128*32;
    u16* pw1   = us + uo; uo += 128*128;
    u16* pw2   = us + uo; uo += 128*128;
    u16* pm0   = us + uo; uo += 128*64;
    u16* pm1   = us + uo; uo += 128*128;
    u16* pm2   = us + uo; uo += 128*128;
    u16* pwih  = us + uo; uo += (size_t)1024*384;
    u16* pwhh  = us + uo; uo += (size_t)1024*256;
    u16* hb0   = us + uo; uo += (size_t)Bn*LH;
    u16* hb1   = us + uo; uo += (size_t)Bn*LH;

    hipMemsetAsync(bar, 0, 256, stream);
    hipMemsetAsync(hb0, 0, (size_t)Bn*LH*sizeof(u16), stream);

    k_pack<<<16,   256, 0, stream>>>(re_w0, pw0, 128, 32, 32);
    k_pack<<<64,   256, 0, stream>>>(re_w1, pw1, 128, 128, 128);
    k_pack<<<64,   256, 0, stream>>>(re_w2, pw2, 128, 128, 128);
    k_pack<<<32,   256, 0, stream>>>(me_w0, pm0, 128, 40, 64);
    k_pack<<<64,   256, 0, stream>>>(me_w1, pm1, 128, 128, 128);
    k_pack<<<64,   256, 0, stream>>>(me_w2, pm2, 128, 128, 128);
    k_pack_gi<<<1536, 256, 0, stream>>>(W_ih, pwih, 384);
    k_pack_gi<<<1024, 256, 0, stream>>>(W_hh, pwhh, 256);
    k_dtv<<<64, 256, 0, stream>>>(obs, dtv);

    k_embed<<<16384, 256, 0, stream>>>(obs, pw0, re_b0, pw1, re_b1, pw2, re_b2,
                                       li_bf, rl);
    k_market<<<512, 256, 0, stream>>>(obs, pm0, me_b0, pm1, me_b1, pm2, me_b2,
                                      li_bf);
    k_xw<<<128, 256, 0, stream>>>(li_bf, pwih, b_ih, xw4);

    k_lstm_all<<<64, 256, 0, stream>>>(xw4, pwhh, W_dt, dtv, hb0, hb1,
                                       hout, cb, bar);

    k_heads<<<256, 256, 0, stream>>>(hout, cb, rl,
        a_w0, a_b0, a_w1, a_b1, c_w0, c_b0, c_w1, c_b1, lstd, out);
}

// Round 4
// 600.253 us; speedup vs baseline: 4.0319x; 1.3316x over previous
//
#include <hip/hip_runtime.h>
#include <hip/hip_bf16.h>
#include <math.h>

#define Bn 256
#define Tn 64
#define OBSD 1000
#define NR 30
#define HD 128
#define LH 256
#define LIN 384
#define TDI 26

#define AM_OFF 0
#define ALS_OFF 15360
#define V_OFF 30720
#define H_OFF 30976
#define C_OFF 96512

typedef unsigned short u16;
typedef short bf16x8 __attribute__((ext_vector_type(8)));
typedef float f32x4 __attribute__((ext_vector_type(4)));

__device__ __forceinline__ float sigm(float x){ return 1.f/(1.f+__expf(-x)); }
__device__ __forceinline__ float tanhfast(float x){
    float ax = fabsf(x);
    float e = __expf(2.f*ax);
    float t = 1.f - 2.f/(e+1.f);
    return copysignf(t, x);
}

__device__ __forceinline__ u16 f2b(float f){
    union { __hip_bfloat16 h; u16 u; } cv;
    cv.h = __float2bfloat16(f);
    return cv.u;
}

#define MFMA(a,b,c) __builtin_amdgcn_mfma_f32_16x16x32_bf16(a,b,c,0,0,0)

// ---------------- packing kernels ----------------
// pack W[N][K] (fp32, row-major [out][in]) into bf16 MFMA B-fragment order:
// frag chunk (ntile, kc): lane l holds W[ntile*16 + (l&15)][kc*32 + (l>>4)*8 + e]
__global__ void k_pack(const float* __restrict__ src, u16* __restrict__ dst,
                       int N, int K, int Kpad)
{
    int t = blockIdx.x*256 + threadIdx.x;
    if (t >= N*Kpad) return;
    int j = t / Kpad, k = t - j*Kpad;
    float v = (k < K) ? src[j*K + k] : 0.f;
    int ntile = j>>4, jr = j&15, kc = k>>5, ko = k&31;
    int lane = ((ko>>3)<<4) | jr, elem = ko&7;
    int KC = Kpad>>5;
    dst[(size_t)(((ntile*KC + kc)*64) + lane)*8 + elem] = f2b(v);
}

// gate-interleaved pack for W_ih / W_hh (N=1024 rows, 4 gates of 256):
// packed col c = nt*16 + jr, nt = jg*4 + g  <->  src row = g*256 + jg*16 + jr
__global__ void k_pack_gi(const float* __restrict__ src, u16* __restrict__ dst, int K)
{
    int KC = K >> 5;
    int t = blockIdx.x*256 + threadIdx.x;
    if (t >= 1024*K) return;
    int n = t / K, k = t - n*K;
    int nt = n>>4, jr = n&15;
    int jg = nt>>2, g = nt&3;
    float v = src[(size_t)(g*256 + jg*16 + jr)*K + k];
    int kc = k>>5, ko = k&31;
    int lane = ((ko>>3)<<4) | jr, e = ko&7;
    dst[(size_t)(((nt*KC + kc)*64) + lane)*8 + e] = f2b(v);
}

// dtv[t*256 + b] = obs[(b*64+t)*OBSD + TDI]
__global__ void k_dtv(const float* __restrict__ obs, float* __restrict__ dtv)
{
    int idx = blockIdx.x*256 + threadIdx.x;   // 16384
    int b = idx >> 6, t = idx & 63;
    dtv[t*256 + b] = obs[(size_t)idx*OBSD + TDI];
}

// ---------------- runner embed (MFMA) ----------------
__global__ __launch_bounds__(256) void k_embed(
    const float* __restrict__ obs,
    const u16* __restrict__ pw0, const float* __restrict__ re_b0,
    const u16* __restrict__ pw1, const float* __restrict__ re_b1,
    const u16* __restrict__ pw2, const float* __restrict__ re_b2,
    u16* __restrict__ li_bf, float* __restrict__ runner_last)
{
    __shared__ __align__(16) u16 xr[32*40];
    __shared__ __align__(16) u16 act1[32*136];
    __shared__ __align__(16) u16 act2[32*136];
    __shared__ float bs0[128], bs1[128], bs2[128];

    int bt = blockIdx.x, tid = threadIdx.x;
    const float* row = obs + (size_t)bt*OBSD;

    for (int idx=tid; idx<1024; idx+=256){
        int r = idx>>5, k = idx&31;
        float v = 0.f;
        if (r < 30) v = (k<24) ? row[30 + r*24 + k] : row[760 + r*8 + (k-24)];
        xr[r*40 + k] = f2b(v);
    }
    if (tid < 128){ bs0[tid]=re_b0[tid]; bs1[tid]=re_b1[tid]; bs2[tid]=re_b2[tid]; }
    __syncthreads();

    int lane = tid & 63, wv = tid >> 6;
    int lr = lane & 15, lk = lane >> 4;
    f32x4 zero = {0.f,0.f,0.f,0.f};

    f32x4 d[2][2];
    {
        bf16x8 a0 = *(const bf16x8*)(xr + lr*40      + lk*8);
        bf16x8 a1 = *(const bf16x8*)(xr + (16+lr)*40 + lk*8);
        #pragma unroll
        for (int ns=0; ns<2; ns++){
            int n = 2*wv + ns;
            bf16x8 b = *(const bf16x8*)(pw0 + (size_t)(n*64 + lane)*8);
            d[0][ns] = MFMA(a0, b, zero);
            d[1][ns] = MFMA(a1, b, zero);
        }
    }
    #pragma unroll
    for (int m=0;m<2;m++)
        #pragma unroll
        for (int ns=0;ns<2;ns++){
            int col = (2*wv+ns)*16 + lr;
            float bias = bs0[col];
            #pragma unroll
            for (int r=0;r<4;r++){
                int rw = m*16 + lk*4 + r;
                act1[rw*136 + col] = f2b(fmaxf(d[m][ns][r] + bias, 0.f));
            }
        }
    __syncthreads();

    #pragma unroll
    for (int m=0;m<2;m++)
        #pragma unroll
        for (int ns=0;ns<2;ns++) d[m][ns] = zero;
    #pragma unroll
    for (int kc=0; kc<4; kc++){
        bf16x8 a0 = *(const bf16x8*)(act1 + lr*136      + kc*32 + lk*8);
        bf16x8 a1 = *(const bf16x8*)(act1 + (16+lr)*136 + kc*32 + lk*8);
        #pragma unroll
        for (int ns=0; ns<2; ns++){
            int n = 2*wv + ns;
            bf16x8 b = *(const bf16x8*)(pw1 + (size_t)((n*4 + kc)*64 + lane)*8);
            d[0][ns] = MFMA(a0, b, d[0][ns]);
            d[1][ns] = MFMA(a1, b, d[1][ns]);
        }
    }
    #pragma unroll
    for (int m=0;m<2;m++)
        #pragma unroll
        for (int ns=0;ns<2;ns++){
            int col = (2*wv+ns)*16 + lr;
            float bias = bs1[col];
            #pragma unroll
            for (int r=0;r<4;r++){
                int rw = m*16 + lk*4 + r;
                act2[rw*136 + col] = f2b(fmaxf(d[m][ns][r] + bias, 0.f));
            }
        }
    __syncthreads();

    #pragma unroll
    for (int m=0;m<2;m++)
        #pragma unroll
        for (int ns=0;ns<2;ns++) d[m][ns] = zero;
    #pragma unroll
    for (int kc=0; kc<4; kc++){
        bf16x8 a0 = *(const bf16x8*)(act2 + lr*136      + kc*32 + lk*8);
        bf16x8 a1 = *(const bf16x8*)(act2 + (16+lr)*136 + kc*32 + lk*8);
        #pragma unroll
        for (int ns=0; ns<2; ns++){
            int n = 2*wv + ns;
            bf16x8 b = *(const bf16x8*)(pw2 + (size_t)((n*4 + kc)*64 + lane)*8);
            d[0][ns] = MFMA(a0, b, d[0][ns]);
            d[1][ns] = MFMA(a1, b, d[1][ns]);
        }
    }

    u16* li = li_bf + (size_t)bt*LIN;
    bool last = ((bt & 63) == 63);
    int bb = bt >> 6;
    #pragma unroll
    for (int ns=0; ns<2; ns++){
        int col = (2*wv+ns)*16 + lr;
        float bias = bs2[col];
        float sum = 0.f, mx = -3.4e38f;
        float vals[2][4];
        #pragma unroll
        for (int m=0;m<2;m++)
            #pragma unroll
            for (int r=0;r<4;r++){
                int rw = m*16 + lk*4 + r;
                float v = d[m][ns][r] + bias;
                vals[m][r] = v;
                bool ok = rw < 30;
                sum += ok ? v : 0.f;
                mx = fmaxf(mx, ok ? v : -3.4e38f);
            }
        sum += __shfl_xor(sum, 16); sum += __shfl_xor(sum, 32);
        mx = fmaxf(mx, __shfl_xor(mx, 16)); mx = fmaxf(mx, __shfl_xor(mx, 32));
        if (lane < 16){
            li[128 + col] = f2b(sum * (1.0f/30.0f));
            li[256 + col] = f2b(mx);
        }
        if (last){
            #pragma unroll
            for (int m=0;m<2;m++)
                #pragma unroll
                for (int r=0;r<4;r++){
                    int rw = m*16 + lk*4 + r;
                    if (rw < 30) runner_last[(size_t)bb*3840 + rw*128 + col] = vals[m][r];
                }
        }
    }
}

// ---------------- market embed (MFMA), 32 rows per block ----------------
__global__ __launch_bounds__(256) void k_market(
    const float* __restrict__ obs,
    const u16* __restrict__ pm0, const float* __restrict__ me_b0,
    const u16* __restrict__ pm1, const float* __restrict__ me_b1,
    const u16* __restrict__ pm2, const float* __restrict__ me_b2,
    u16* __restrict__ li_bf)
{
    __shared__ __align__(16) u16 xm[32*72];
    __shared__ __align__(16) u16 ma1[32*136];
    __shared__ __align__(16) u16 ma2[32*136];
    __shared__ float bs0[128], bs1[128], bs2[128];

    int bt0 = blockIdx.x*32, tid = threadIdx.x;
    for (int idx=tid; idx<2048; idx+=256){
        int r = idx>>6, k = idx&63;
        const float* row = obs + (size_t)(bt0+r)*OBSD;
        float v = 0.f;
        if (k < 30) v = row[k];
        else if (k < 40) v = row[720 + k];
        xm[r*72 + k] = f2b(v);
    }
    if (tid < 128){ bs0[tid]=me_b0[tid]; bs1[tid]=me_b1[tid]; bs2[tid]=me_b2[tid]; }
    __syncthreads();

    int lane = tid & 63, wv = tid >> 6;
    int lr = lane & 15, lk = lane >> 4;
    f32x4 zero = {0.f,0.f,0.f,0.f};
    f32x4 d[2][2];

    #pragma unroll
    for (int m=0;m<2;m++)
        #pragma unroll
        for (int ns=0;ns<2;ns++) d[m][ns] = zero;
    #pragma unroll
    for (int kc=0; kc<2; kc++){
        bf16x8 a0 = *(const bf16x8*)(xm + lr*72      + kc*32 + lk*8);
        bf16x8 a1 = *(const bf16x8*)(xm + (16+lr)*72 + kc*32 + lk*8);
        #pragma unroll
        for (int ns=0; ns<2; ns++){
            int n = 2*wv + ns;
            bf16x8 b = *(const bf16x8*)(pm0 + (size_t)((n*2 + kc)*64 + lane)*8);
            d[0][ns] = MFMA(a0, b, d[0][ns]);
            d[1][ns] = MFMA(a1, b, d[1][ns]);
        }
    }
    #pragma unroll
    for (int m=0;m<2;m++)
        #pragma unroll
        for (int ns=0;ns<2;ns++){
            int col = (2*wv+ns)*16 + lr;
            float bias = bs0[col];
            #pragma unroll
            for (int r=0;r<4;r++){
                int rw = m*16 + lk*4 + r;
                ma1[rw*136 + col] = f2b(fmaxf(d[m][ns][r] + bias, 0.f));
            }
        }
    __syncthreads();

    #pragma unroll
    for (int m=0;m<2;m++)
        #pragma unroll
        for (int ns=0;ns<2;ns++) d[m][ns] = zero;
    #pragma unroll
    for (int kc=0; kc<4; kc++){
        bf16x8 a0 = *(const bf16x8*)(ma1 + lr*136      + kc*32 + lk*8);
        bf16x8 a1 = *(const bf16x8*)(ma1 + (16+lr)*136 + kc*32 + lk*8);
        #pragma unroll
        for (int ns=0; ns<2; ns++){
            int n = 2*wv + ns;
            bf16x8 b = *(const bf16x8*)(pm1 + (size_t)((n*4 + kc)*64 + lane)*8);
            d[0][ns] = MFMA(a0, b, d[0][ns]);
            d[1][ns] = MFMA(a1, b, d[1][ns]);
        }
    }
    #pragma unroll
    for (int m=0;m<2;m++)
        #pragma unroll
        for (int ns=0;ns<2;ns++){
            int col = (2*wv+ns)*16 + lr;
            float bias = bs1[col];
            #pragma unroll
            for (int r=0;r<4;r++){
                int rw = m*16 + lk*4 + r;
                ma2[rw*136 + col] = f2b(fmaxf(d[m][ns][r] + bias, 0.f));
            }
        }
    __syncthreads();

    #pragma unroll
    for (int m=0;m<2;m++)
        #pragma unroll
        for (int ns=0;ns<2;ns++) d[m][ns] = zero;
    #pragma unroll
    for (int kc=0; kc<4; kc++){
        bf16x8 a0 = *(const bf16x8*)(ma2 + lr*136      + kc*32 + lk*8);
        bf16x8 a1 = *(const bf16x8*)(ma2 + (16+lr)*136 + kc*32 + lk*8);
        #pragma unroll
        for (int ns=0; ns<2; ns++){
            int n = 2*wv + ns;
            bf16x8 b = *(const bf16x8*)(pm2 + (size_t)((n*4 + kc)*64 + lane)*8);
            d[0][ns] = MFMA(a0, b, d[0][ns]);
            d[1][ns] = MFMA(a1, b, d[1][ns]);
        }
    }
    #pragma unroll
    for (int m=0;m<2;m++)
        #pragma unroll
        for (int ns=0;ns<2;ns++){
            int col = (2*wv+ns)*16 + lr;
            float bias = bs2[col];
            #pragma unroll
            for (int r=0;r<4;r++){
                int rw = m*16 + lk*4 + r;
                li_bf[(size_t)(bt0+rw)*LIN + col] = f2b(d[m][ns][r] + bias);
            }
        }
}

// ---------------- xW precompute (MFMA) ----------------
// writes xw[btrow][(jg*4+g)*16 + lr]  (packed gate-col order, nt = jg*4+g)
__global__ __launch_bounds__(256) void k_xw(
    const u16* __restrict__ A, const u16* __restrict__ pwih,
    const float* __restrict__ b_ih, float* __restrict__ xw)
{
    int tid = threadIdx.x;
    int lane = tid & 63, wv = tid >> 6;
    int lr = lane & 15, lk = lane >> 4;
    int r0 = (blockIdx.x*4 + wv) * 32;

    bf16x8 a[2][12];
    #pragma unroll
    for (int m=0;m<2;m++)
        #pragma unroll
        for (int kc=0;kc<12;kc++)
            a[m][kc] = *(const bf16x8*)(A + (size_t)(r0+m*16+lr)*384 + kc*32 + lk*8);

    for (int jg=0; jg<16; jg++){
        f32x4 acc[2][4];
        #pragma unroll
        for (int g=0; g<4; g++){
            float bias = b_ih[g*256 + jg*16 + lr];
            f32x4 v = {bias,bias,bias,bias};
            acc[0][g]=v; acc[1][g]=v;
        }
        #pragma unroll
        for (int kc=0; kc<12; kc++){
            bf16x8 b0 = *(const bf16x8*)(pwih + (size_t)(((jg*4+0)*12+kc)*64+lane)*8);
            bf16x8 b1 = *(const bf16x8*)(pwih + (size_t)(((jg*4+1)*12+kc)*64+lane)*8);
            bf16x8 b2 = *(const bf16x8*)(pwih + (size_t)(((jg*4+2)*12+kc)*64+lane)*8);
            bf16x8 b3 = *(const bf16x8*)(pwih + (size_t)(((jg*4+3)*12+kc)*64+lane)*8);
            #pragma unroll
            for (int m=0;m<2;m++){
                acc[m][0] = MFMA(a[m][kc], b0, acc[m][0]);
                acc[m][1] = MFMA(a[m][kc], b1, acc[m][1]);
                acc[m][2] = MFMA(a[m][kc], b2, acc[m][2]);
                acc[m][3] = MFMA(a[m][kc], b3, acc[m][3]);
            }
        }
        #pragma unroll
        for (int m=0;m<2;m++)
            #pragma unroll
            for (int g=0;g<4;g++)
                #pragma unroll
                for (int r=0;r<4;r++)
                    xw[(size_t)(r0+m*16+lk*4+r)*1024 + (jg*4+g)*16 + lr] = acc[m][g][r];
    }
}

// ---------------- pairwise persistent LSTM ----------------
// 32 blocks: pair p = blk>>1 owns batches p*16..+15; half = blk&1 owns
// gate-cols for j in [half*128, half*128+128) (jg = half*8 .. +8).
// W_hh half (512 gate-cols) in registers (64 bf16x8). Per step: MFMA,
// activations, write 4KB h-slice, release flag, poll partner, reload h.
__global__ __launch_bounds__(256,1) void k_lstm_pair(
    const float* __restrict__ xw, const u16* __restrict__ pwhh,
    const float* __restrict__ W_dt, const float* __restrict__ dtv,
    u16* __restrict__ hb0, u16* __restrict__ hb1,
    float* __restrict__ hout, float* __restrict__ cout,
    unsigned int* __restrict__ flags)
{
    int tid = threadIdx.x;
    int lane = tid & 63, wv = tid >> 6;
    int lr = lane & 15, lk = lane >> 4;
    int blk = blockIdx.x;
    int p = blk >> 1, hf = blk & 1;
    int bb0 = p*16;
    int jg0 = hf*8 + wv*2;

    // W_hh fragments for this wave's 2 jg groups x 4 gates
    bf16x8 bfr[2][4][8];
    #pragma unroll
    for (int jl=0;jl<2;jl++)
        #pragma unroll
        for (int g=0;g<4;g++)
            #pragma unroll
            for (int kc=0;kc<8;kc++)
                bfr[jl][g][kc] = *(const bf16x8*)(pwhh + (size_t)((((jg0+jl)*4+g)*8+kc)*64+lane)*8);

    float wdt0 = W_dt[jg0*16 + lr];
    float wdt1 = W_dt[(jg0+1)*16 + lr];

    float cst[2][4] = {{0.f,0.f,0.f,0.f},{0.f,0.f,0.f,0.f}};
    bf16x8 a[8];
    #pragma unroll
    for (int kc=0;kc<8;kc++) a[kc] = (bf16x8)(short)0;

    int bth = bb0 + lk*4;   // batch base of this thread's 4 rows

    // current-step xw / dt
    float xwn[2][4][4];
    #pragma unroll
    for (int jl=0;jl<2;jl++)
        #pragma unroll
        for (int g=0;g<4;g++)
            #pragma unroll
            for (int r=0;r<4;r++)
                xwn[jl][g][r] = xw[(size_t)((bth+r)*64 + 0)*1024 + ((jg0+jl)*4+g)*16 + lr];
    float4 dtn = *(const float4*)(dtv + 0*256 + bth);

    for (int t=0; t<64; t++){
        // prefetch next step's xw/dt (independent of recurrence)
        float xwp_[2][4][4];
        float4 dtp = dtn;
        if (t < 63){
            #pragma unroll
            for (int jl=0;jl<2;jl++)
                #pragma unroll
                for (int g=0;g<4;g++)
                    #pragma unroll
                    for (int r=0;r<4;r++)
                        xwp_[jl][g][r] = xw[(size_t)((bth+r)*64 + (t+1))*1024 + ((jg0+jl)*4+g)*16 + lr];
            dtp = *(const float4*)(dtv + (t+1)*256 + bth);
        }

        f32x4 acc[2][4];
        #pragma unroll
        for (int jl=0;jl<2;jl++)
            #pragma unroll
            for (int g=0;g<4;g++){
                f32x4 v;
                v[0]=xwn[jl][g][0]; v[1]=xwn[jl][g][1];
                v[2]=xwn[jl][g][2]; v[3]=xwn[jl][g][3];
                acc[jl][g] = v;
            }

        #pragma unroll
        for (int kc=0; kc<8; kc++){
            #pragma unroll
            for (int jl=0;jl<2;jl++){
                acc[jl][0] = MFMA(a[kc], bfr[jl][0][kc], acc[jl][0]);
                acc[jl][1] = MFMA(a[kc], bfr[jl][1][kc], acc[jl][1]);
                acc[jl][2] = MFMA(a[kc], bfr[jl][2][kc], acc[jl][2]);
                acc[jl][3] = MFMA(a[kc], bfr[jl][3][kc], acc[jl][3]);
            }
        }

        u16* hw = (t&1) ? hb1 : hb0;
        #pragma unroll
        for (int jl=0;jl<2;jl++){
            float wdt = jl ? wdt1 : wdt0;
            int jcol = (jg0+jl)*16 + lr;
            #pragma unroll
            for (int r=0;r<4;r++){
                float gi = sigm(acc[jl][0][r]);
                float gf = sigm(acc[jl][1][r] + wdt*((r==0)?dtn.x:(r==1)?dtn.y:(r==2)?dtn.z:dtn.w));
                float gg = tanhfast(acc[jl][2][r]);
                float go = sigm(acc[jl][3][r]);
                float cn = fmaf(gf, cst[jl][r], gi*gg);
                cst[jl][r] = cn;
                float hv = go * tanhfast(cn);
                hw[(size_t)(bth+r)*256 + jcol] = f2b(hv);
                if (t == 63){
                    hout[(size_t)(bth+r)*256 + jcol] = hv;
                    cout[(size_t)(bth+r)*256 + jcol] = cn;
                }
            }
        }

        if (t < 63){
            __syncthreads();   // all waves' h stores drained (implicit vmcnt(0))
            if (tid == 0){
                __hip_atomic_store(&flags[blk*16], (unsigned)(t+1),
                                   __ATOMIC_RELEASE, __HIP_MEMORY_SCOPE_AGENT);
                while (__hip_atomic_load(&flags[(blk^1)*16],
                        __ATOMIC_RELAXED, __HIP_MEMORY_SCOPE_AGENT) < (unsigned)(t+1))
                    __builtin_amdgcn_s_sleep(1);
                (void)__hip_atomic_load(&flags[(blk^1)*16],
                        __ATOMIC_ACQUIRE, __HIP_MEMORY_SCOPE_AGENT);
            }
            __syncthreads();
            const u16* hr = (t&1) ? hb1 : hb0;
            #pragma unroll
            for (int kc=0; kc<8; kc++)
                a[kc] = *(const bf16x8*)(hr + (size_t)(bb0+lr)*256 + kc*32 + lk*8);
            #pragma unroll
            for (int jl=0;jl<2;jl++)
                #pragma unroll
                for (int g=0;g<4;g++)
                    #pragma unroll
                    for (int r=0;r<4;r++)
                        xwn[jl][g][r] = xwp_[jl][g][r];
            dtn = dtp;
        }
    }
}

// ---------------- heads (fp32) ----------------
__device__ __forceinline__ void dense30(
    const float* in, int istride,
    const float* __restrict__ W, int wstride, int K,
    const float* __restrict__ bias, const float* extra,
    float* outp, int ostride, bool relu, int j, int rh)
{
    float acc[15];
    #pragma unroll
    for (int i=0;i<15;i++) acc[i]=0.f;
    const float* w = W + j*wstride;
    for (int k=0;k<K;k+=4){
        float4 wv = *(const float4*)(w+k);
        #pragma unroll
        for (int i=0;i<15;i++){
            float4 xv = *(const float4*)(in + (rh+2*i)*istride + k);
            acc[i] = fmaf(wv.x,xv.x,acc[i]);
            acc[i] = fmaf(wv.y,xv.y,acc[i]);
            acc[i] = fmaf(wv.z,xv.z,acc[i]);
            acc[i] = fmaf(wv.w,xv.w,acc[i]);
        }
    }
    float bb = bias[j] + (extra ? extra[j] : 0.f);
    #pragma unroll
    for (int i=0;i<15;i++){
        float v = acc[i]+bb;
        outp[(rh+2*i)*ostride+j] = relu ? fmaxf(v,0.f) : v;
    }
}

__device__ __forceinline__ float dense1(
    const float* in, const float* __restrict__ W,
    const float* __restrict__ bias, int K, int j)
{
    const float* w = W + j*K;
    float s = 0.f;
    for (int k=0;k<K;k+=4){
        float4 wv = *(const float4*)(w+k);
        float4 xv = *(const float4*)(in+k);
        s = fmaf(wv.x,xv.x,s); s = fmaf(wv.y,xv.y,s);
        s = fmaf(wv.z,xv.z,s); s = fmaf(wv.w,xv.w,s);
    }
    return s + bias[j];
}

__global__ __launch_bounds__(256) void k_heads(
    const float* __restrict__ h, const float* __restrict__ cbuf,
    const float* __restrict__ rl,
    const float* __restrict__ a_w0, const float* __restrict__ a_b0,
    const float* __restrict__ a_w1, const float* __restrict__ a_b1,
    const float* __restrict__ c_w0, const float* __restrict__ c_b0,
    const float* __restrict__ c_w1, const float* __restrict__ c_b1,
    const float* __restrict__ log_std,
    float* __restrict__ out)
{
    __shared__ __align__(16) float hv[LH];
    __shared__ __align__(16) float rls[NR][HD];
    __shared__ __align__(16) float hid[NR][HD];
    __shared__ __align__(16) float dot2[HD];
    __shared__ __align__(16) float red[128];

    int b = blockIdx.x, tid = threadIdx.x;
    hv[tid] = h[b*LH + tid];
    for (int idx=tid; idx<NR*HD; idx+=256) rls[idx>>7][idx&127] = rl[(size_t)b*NR*HD + idx];
    __syncthreads();

    if (tid < 128){
        const float* w = a_w0 + tid*LIN + HD;
        float s = 0.f;
        for (int k=0;k<LH;k+=4){
            float4 wv = *(const float4*)(w+k);
            s = fmaf(wv.x,hv[k],s); s = fmaf(wv.y,hv[k+1],s);
            s = fmaf(wv.z,hv[k+2],s); s = fmaf(wv.w,hv[k+3],s);
        }
        dot2[tid] = s;
    }
    __syncthreads();

    int j = tid & 127, rh = tid >> 7;
    dense30(&rls[0][0], HD, a_w0, LIN, HD, a_b0, dot2, &hid[0][0], HD, true, j, rh);
    __syncthreads();

    if (tid < 60){
        int r = tid >> 1, o = tid & 1;
        const float* w = a_w1 + o*HD;
        float s = a_b1[o];
        for (int k=0;k<HD;k++) s = fmaf(hid[r][k], w[k], s);
        out[AM_OFF + b*60 + tid] = s;
        out[ALS_OFF + b*60 + tid] = log_std[tid];
    }

    float term = 0.f;
    if (tid < 128) term = fmaxf(dense1(hv, c_w0, c_b0, LH, tid), 0.f) * c_w1[tid];
    if (tid < 128) red[tid] = term;
    __syncthreads();
    for (int s2=64; s2>0; s2>>=1){
        if (tid < s2) red[tid] += red[tid+s2];
        __syncthreads();
    }
    if (tid == 0) out[V_OFF + b] = red[0] + c_b1[0];

    out[H_OFF + b*LH + tid] = hv[tid];
    out[C_OFF + b*LH + tid] = cbuf[b*LH + tid];
}

extern "C" void kernel_launch(void* const* d_in, const int* in_sizes, int n_in,
                              void* d_out, int out_size, void* d_ws, size_t ws_size,
                              hipStream_t stream)
{
    const float* obs   = (const float*)d_in[0];
    const float* re_w0 = (const float*)d_in[1];
    const float* re_b0 = (const float*)d_in[2];
    const float* re_w1 = (const float*)d_in[3];
    const float* re_b1 = (const float*)d_in[4];
    const float* re_w2 = (const float*)d_in[5];
    const float* re_b2 = (const float*)d_in[6];
    const float* me_w0 = (const float*)d_in[7];
    const float* me_b0 = (const float*)d_in[8];
    const float* me_w1 = (const float*)d_in[9];
    const float* me_b1 = (const float*)d_in[10];
    const float* me_w2 = (const float*)d_in[11];
    const float* me_b2 = (const float*)d_in[12];
    const float* W_ih  = (const float*)d_in[13];
    const float* b_ih  = (const float*)d_in[14];
    const float* W_hh  = (const float*)d_in[15];
    const float* W_dt  = (const float*)d_in[16];
    const float* a_w0  = (const float*)d_in[17];
    const float* a_b0  = (const float*)d_in[18];
    const float* a_w1  = (const float*)d_in[19];
    const float* a_b1  = (const float*)d_in[20];
    const float* c_w0  = (const float*)d_in[21];
    const float* c_b0  = (const float*)d_in[22];
    const float* c_w1  = (const float*)d_in[23];
    const float* c_b1  = (const float*)d_in[24];
    const float* lstd  = (const float*)d_in[25];
    float* out = (float*)d_out;

    float* ws = (float*)d_ws;
    size_t off = 0;
    float* xw4  = ws + off; off += (size_t)16384*1024;
    float* hout = ws + off; off += (size_t)Bn*LH;
    float* cb   = ws + off; off += (size_t)Bn*LH;
    float* rl   = ws + off; off += (size_t)Bn*NR*HD;
    float* dtv  = ws + off; off += (size_t)16384;
    unsigned int* flags = (unsigned int*)(ws + off); off += 512;

    u16* us = (u16*)(ws + off);
    size_t uo = 0;
    u16* li_bf = us + uo; uo += (size_t)16384*LIN;
    u16* pw0   = us + uo; uo += 128*32;
    u16* pw1   = us + uo; uo += 128*128;
    u16* pw2   = us + uo; uo += 128*128;
    u16* pm0   = us + uo; uo += 128*64;
    u16* pm1   = us + uo; uo += 128*128;
    u16* pm2   = us + uo; uo += 128*128;
    u16* pwih  = us + uo; uo += (size_t)1024*384;
    u16* pwhh  = us + uo; uo += (size_t)1024*256;
    u16* hb0   = us + uo; uo += (size_t)Bn*LH;
    u16* hb1   = us + uo; uo += (size_t)Bn*LH;

    hipMemsetAsync(flags, 0, 2048, stream);

    k_pack<<<16,   256, 0, stream>>>(re_w0, pw0, 128, 32, 32);
    k_pack<<<64,   256, 0, stream>>>(re_w1, pw1, 128, 128, 128);
    k_pack<<<64,   256, 0, stream>>>(re_w2, pw2, 128, 128, 128);
    k_pack<<<32,   256, 0, stream>>>(me_w0, pm0, 128, 40, 64);
    k_pack<<<64,   256, 0, stream>>>(me_w1, pm1, 128, 128, 128);
    k_pack<<<64,   256, 0, stream>>>(me_w2, pm2, 128, 128, 128);
    k_pack_gi<<<1536, 256, 0, stream>>>(W_ih, pwih, 384);
    k_pack_gi<<<1024, 256, 0, stream>>>(W_hh, pwhh, 256);
    k_dtv<<<64, 256, 0, stream>>>(obs, dtv);

    k_embed<<<16384, 256, 0, stream>>>(obs, pw0, re_b0, pw1, re_b1, pw2, re_b2,
                                       li_bf, rl);
    k_market<<<512, 256, 0, stream>>>(obs, pm0, me_b0, pm1, me_b1, pm2, me_b2,
                                      li_bf);
    k_xw<<<128, 256, 0, stream>>>(li_bf, pwih, b_ih, xw4);

    k_lstm_pair<<<32, 256, 0, stream>>>(xw4, pwhh, W_dt, dtv, hb0, hb1,
                                        hout, cb, flags);

    k_heads<<<256, 256, 0, stream>>>(hout, cb, rl,
        a_w0, a_b0, a_w1, a_b1, c_w0, c_b0, c_w1, c_b1, lstd, out);
}

// Round 5
// 573.724 us; speedup vs baseline: 4.2183x; 1.0462x over previous
//
#include <hip/hip_runtime.h>
#include <hip/hip_bf16.h>
#include <math.h>

#define Bn 256
#define Tn 64
#define OBSD 1000
#define NR 30
#define HD 128
#define LH 256
#define LIN 384
#define TDI 26

#define AM_OFF 0
#define ALS_OFF 15360
#define V_OFF 30720
#define H_OFF 30976
#define C_OFF 96512

typedef unsigned short u16;
typedef short bf16x8 __attribute__((ext_vector_type(8)));
typedef float f32x4 __attribute__((ext_vector_type(4)));

__device__ __forceinline__ float sigm(float x){ return 1.f/(1.f+__expf(-x)); }
__device__ __forceinline__ float tanhfast(float x){
    float ax = fabsf(x);
    float e = __expf(2.f*ax);
    float t = 1.f - 2.f/(e+1.f);
    return copysignf(t, x);
}

__device__ __forceinline__ u16 f2b(float f){
    union { __hip_bfloat16 h; u16 u; } cv;
    cv.h = __float2bfloat16(f);
    return cv.u;
}

// system-coherent (L3) access helpers — no L2 writeback/invalidate needed
__device__ __forceinline__ bf16x8 ld_b128_sys(const u16* p){
    bf16x8 r;
    asm volatile("global_load_dwordx4 %0, %1, off sc0 sc1"
                 : "=v"(r) : "v"(p) : "memory");
    return r;
}
__device__ __forceinline__ void st_b16_sys(u16* p, unsigned v){
    asm volatile("global_store_short %0, %1, off sc0 sc1"
                 :: "v"(p), "v"(v) : "memory");
}

#define MFMA(a,b,c) __builtin_amdgcn_mfma_f32_16x16x32_bf16(a,b,c,0,0,0)

// ---------------- packing kernels ----------------
__global__ void k_pack(const float* __restrict__ src, u16* __restrict__ dst,
                       int N, int K, int Kpad)
{
    int t = blockIdx.x*256 + threadIdx.x;
    if (t >= N*Kpad) return;
    int j = t / Kpad, k = t - j*Kpad;
    float v = (k < K) ? src[j*K + k] : 0.f;
    int ntile = j>>4, jr = j&15, kc = k>>5, ko = k&31;
    int lane = ((ko>>3)<<4) | jr, elem = ko&7;
    int KC = Kpad>>5;
    dst[(size_t)(((ntile*KC + kc)*64) + lane)*8 + elem] = f2b(v);
}

// gate-interleaved pack for W_ih / W_hh: nt = jg*4 + g <-> src row g*256+jg*16+jr
__global__ void k_pack_gi(const float* __restrict__ src, u16* __restrict__ dst, int K)
{
    int KC = K >> 5;
    int t = blockIdx.x*256 + threadIdx.x;
    if (t >= 1024*K) return;
    int n = t / K, k = t - n*K;
    int nt = n>>4, jr = n&15;
    int jg = nt>>2, g = nt&3;
    float v = src[(size_t)(g*256 + jg*16 + jr)*K + k];
    int kc = k>>5, ko = k&31;
    int lane = ((ko>>3)<<4) | jr, e = ko&7;
    dst[(size_t)(((nt*KC + kc)*64) + lane)*8 + e] = f2b(v);
}

__global__ void k_dtv(const float* __restrict__ obs, float* __restrict__ dtv)
{
    int idx = blockIdx.x*256 + threadIdx.x;   // 16384
    int b = idx >> 6, t = idx & 63;
    dtv[t*256 + b] = obs[(size_t)idx*OBSD + TDI];
}

// ---------------- runner embed (MFMA) ----------------
__global__ __launch_bounds__(256) void k_embed(
    const float* __restrict__ obs,
    const u16* __restrict__ pw0, const float* __restrict__ re_b0,
    const u16* __restrict__ pw1, const float* __restrict__ re_b1,
    const u16* __restrict__ pw2, const float* __restrict__ re_b2,
    u16* __restrict__ li_bf, float* __restrict__ runner_last)
{
    __shared__ __align__(16) u16 xr[32*40];
    __shared__ __align__(16) u16 act1[32*136];
    __shared__ __align__(16) u16 act2[32*136];
    __shared__ float bs0[128], bs1[128], bs2[128];

    int bt = blockIdx.x, tid = threadIdx.x;
    const float* row = obs + (size_t)bt*OBSD;

    for (int idx=tid; idx<1024; idx+=256){
        int r = idx>>5, k = idx&31;
        float v = 0.f;
        if (r < 30) v = (k<24) ? row[30 + r*24 + k] : row[760 + r*8 + (k-24)];
        xr[r*40 + k] = f2b(v);
    }
    if (tid < 128){ bs0[tid]=re_b0[tid]; bs1[tid]=re_b1[tid]; bs2[tid]=re_b2[tid]; }
    __syncthreads();

    int lane = tid & 63, wv = tid >> 6;
    int lr = lane & 15, lk = lane >> 4;
    f32x4 zero = {0.f,0.f,0.f,0.f};

    f32x4 d[2][2];
    {
        bf16x8 a0 = *(const bf16x8*)(xr + lr*40      + lk*8);
        bf16x8 a1 = *(const bf16x8*)(xr + (16+lr)*40 + lk*8);
        #pragma unroll
        for (int ns=0; ns<2; ns++){
            int n = 2*wv + ns;
            bf16x8 b = *(const bf16x8*)(pw0 + (size_t)(n*64 + lane)*8);
            d[0][ns] = MFMA(a0, b, zero);
            d[1][ns] = MFMA(a1, b, zero);
        }
    }
    #pragma unroll
    for (int m=0;m<2;m++)
        #pragma unroll
        for (int ns=0;ns<2;ns++){
            int col = (2*wv+ns)*16 + lr;
            float bias = bs0[col];
            #pragma unroll
            for (int r=0;r<4;r++){
                int rw = m*16 + lk*4 + r;
                act1[rw*136 + col] = f2b(fmaxf(d[m][ns][r] + bias, 0.f));
            }
        }
    __syncthreads();

    #pragma unroll
    for (int m=0;m<2;m++)
        #pragma unroll
        for (int ns=0;ns<2;ns++) d[m][ns] = zero;
    #pragma unroll
    for (int kc=0; kc<4; kc++){
        bf16x8 a0 = *(const bf16x8*)(act1 + lr*136      + kc*32 + lk*8);
        bf16x8 a1 = *(const bf16x8*)(act1 + (16+lr)*136 + kc*32 + lk*8);
        #pragma unroll
        for (int ns=0; ns<2; ns++){
            int n = 2*wv + ns;
            bf16x8 b = *(const bf16x8*)(pw1 + (size_t)((n*4 + kc)*64 + lane)*8);
            d[0][ns] = MFMA(a0, b, d[0][ns]);
            d[1][ns] = MFMA(a1, b, d[1][ns]);
        }
    }
    #pragma unroll
    for (int m=0;m<2;m++)
        #pragma unroll
        for (int ns=0;ns<2;ns++){
            int col = (2*wv+ns)*16 + lr;
            float bias = bs1[col];
            #pragma unroll
            for (int r=0;r<4;r++){
                int rw = m*16 + lk*4 + r;
                act2[rw*136 + col] = f2b(fmaxf(d[m][ns][r] + bias, 0.f));
            }
        }
    __syncthreads();

    #pragma unroll
    for (int m=0;m<2;m++)
        #pragma unroll
        for (int ns=0;ns<2;ns++) d[m][ns] = zero;
    #pragma unroll
    for (int kc=0; kc<4; kc++){
        bf16x8 a0 = *(const bf16x8*)(act2 + lr*136      + kc*32 + lk*8);
        bf16x8 a1 = *(const bf16x8*)(act2 + (16+lr)*136 + kc*32 + lk*8);
        #pragma unroll
        for (int ns=0; ns<2; ns++){
            int n = 2*wv + ns;
            bf16x8 b = *(const bf16x8*)(pw2 + (size_t)((n*4 + kc)*64 + lane)*8);
            d[0][ns] = MFMA(a0, b, d[0][ns]);
            d[1][ns] = MFMA(a1, b, d[1][ns]);
        }
    }

    u16* li = li_bf + (size_t)bt*LIN;
    bool last = ((bt & 63) == 63);
    int bb = bt >> 6;
    #pragma unroll
    for (int ns=0; ns<2; ns++){
        int col = (2*wv+ns)*16 + lr;
        float bias = bs2[col];
        float sum = 0.f, mx = -3.4e38f;
        float vals[2][4];
        #pragma unroll
        for (int m=0;m<2;m++)
            #pragma unroll
            for (int r=0;r<4;r++){
                int rw = m*16 + lk*4 + r;
                float v = d[m][ns][r] + bias;
                vals[m][r] = v;
                bool ok = rw < 30;
                sum += ok ? v : 0.f;
                mx = fmaxf(mx, ok ? v : -3.4e38f);
            }
        sum += __shfl_xor(sum, 16); sum += __shfl_xor(sum, 32);
        mx = fmaxf(mx, __shfl_xor(mx, 16)); mx = fmaxf(mx, __shfl_xor(mx, 32));
        if (lane < 16){
            li[128 + col] = f2b(sum * (1.0f/30.0f));
            li[256 + col] = f2b(mx);
        }
        if (last){
            #pragma unroll
            for (int m=0;m<2;m++)
                #pragma unroll
                for (int r=0;r<4;r++){
                    int rw = m*16 + lk*4 + r;
                    if (rw < 30) runner_last[(size_t)bb*3840 + rw*128 + col] = vals[m][r];
                }
        }
    }
}

// ---------------- market embed (MFMA), 32 rows per block ----------------
__global__ __launch_bounds__(256) void k_market(
    const float* __restrict__ obs,
    const u16* __restrict__ pm0, const float* __restrict__ me_b0,
    const u16* __restrict__ pm1, const float* __restrict__ me_b1,
    const u16* __restrict__ pm2, const float* __restrict__ me_b2,
    u16* __restrict__ li_bf)
{
    __shared__ __align__(16) u16 xm[32*72];
    __shared__ __align__(16) u16 ma1[32*136];
    __shared__ __align__(16) u16 ma2[32*136];
    __shared__ float bs0[128], bs1[128], bs2[128];

    int bt0 = blockIdx.x*32, tid = threadIdx.x;
    for (int idx=tid; idx<2048; idx+=256){
        int r = idx>>6, k = idx&63;
        const float* row = obs + (size_t)(bt0+r)*OBSD;
        float v = 0.f;
        if (k < 30) v = row[k];
        else if (k < 40) v = row[720 + k];
        xm[r*72 + k] = f2b(v);
    }
    if (tid < 128){ bs0[tid]=me_b0[tid]; bs1[tid]=me_b1[tid]; bs2[tid]=me_b2[tid]; }
    __syncthreads();

    int lane = tid & 63, wv = tid >> 6;
    int lr = lane & 15, lk = lane >> 4;
    f32x4 zero = {0.f,0.f,0.f,0.f};
    f32x4 d[2][2];

    #pragma unroll
    for (int m=0;m<2;m++)
        #pragma unroll
        for (int ns=0;ns<2;ns++) d[m][ns] = zero;
    #pragma unroll
    for (int kc=0; kc<2; kc++){
        bf16x8 a0 = *(const bf16x8*)(xm + lr*72      + kc*32 + lk*8);
        bf16x8 a1 = *(const bf16x8*)(xm + (16+lr)*72 + kc*32 + lk*8);
        #pragma unroll
        for (int ns=0; ns<2; ns++){
            int n = 2*wv + ns;
            bf16x8 b = *(const bf16x8*)(pm0 + (size_t)((n*2 + kc)*64 + lane)*8);
            d[0][ns] = MFMA(a0, b, d[0][ns]);
            d[1][ns] = MFMA(a1, b, d[1][ns]);
        }
    }
    #pragma unroll
    for (int m=0;m<2;m++)
        #pragma unroll
        for (int ns=0;ns<2;ns++){
            int col = (2*wv+ns)*16 + lr;
            float bias = bs0[col];
            #pragma unroll
            for (int r=0;r<4;r++){
                int rw = m*16 + lk*4 + r;
                ma1[rw*136 + col] = f2b(fmaxf(d[m][ns][r] + bias, 0.f));
            }
        }
    __syncthreads();

    #pragma unroll
    for (int m=0;m<2;m++)
        #pragma unroll
        for (int ns=0;ns<2;ns++) d[m][ns] = zero;
    #pragma unroll
    for (int kc=0; kc<4; kc++){
        bf16x8 a0 = *(const bf16x8*)(ma1 + lr*136      + kc*32 + lk*8);
        bf16x8 a1 = *(const bf16x8*)(ma1 + (16+lr)*136 + kc*32 + lk*8);
        #pragma unroll
        for (int ns=0; ns<2; ns++){
            int n = 2*wv + ns;
            bf16x8 b = *(const bf16x8*)(pm1 + (size_t)((n*4 + kc)*64 + lane)*8);
            d[0][ns] = MFMA(a0, b, d[0][ns]);
            d[1][ns] = MFMA(a1, b, d[1][ns]);
        }
    }
    #pragma unroll
    for (int m=0;m<2;m++)
        #pragma unroll
        for (int ns=0;ns<2;ns++){
            int col = (2*wv+ns)*16 + lr;
            float bias = bs1[col];
            #pragma unroll
            for (int r=0;r<4;r++){
                int rw = m*16 + lk*4 + r;
                ma2[rw*136 + col] = f2b(fmaxf(d[m][ns][r] + bias, 0.f));
            }
        }
    __syncthreads();

    #pragma unroll
    for (int m=0;m<2;m++)
        #pragma unroll
        for (int ns=0;ns<2;ns++) d[m][ns] = zero;
    #pragma unroll
    for (int kc=0; kc<4; kc++){
        bf16x8 a0 = *(const bf16x8*)(ma2 + lr*136      + kc*32 + lk*8);
        bf16x8 a1 = *(const bf16x8*)(ma2 + (16+lr)*136 + kc*32 + lk*8);
        #pragma unroll
        for (int ns=0; ns<2; ns++){
            int n = 2*wv + ns;
            bf16x8 b = *(const bf16x8*)(pm2 + (size_t)((n*4 + kc)*64 + lane)*8);
            d[0][ns] = MFMA(a0, b, d[0][ns]);
            d[1][ns] = MFMA(a1, b, d[1][ns]);
        }
    }
    #pragma unroll
    for (int m=0;m<2;m++)
        #pragma unroll
        for (int ns=0;ns<2;ns++){
            int col = (2*wv+ns)*16 + lr;
            float bias = bs2[col];
            #pragma unroll
            for (int r=0;r<4;r++){
                int rw = m*16 + lk*4 + r;
                li_bf[(size_t)(bt0+rw)*LIN + col] = f2b(d[m][ns][r] + bias);
            }
        }
}

// ---------------- xW precompute (MFMA) ----------------
// writes xw[btrow][(jg*4+g)*16 + lr]  (packed gate-col order)
__global__ __launch_bounds__(256) void k_xw(
    const u16* __restrict__ A, const u16* __restrict__ pwih,
    const float* __restrict__ b_ih, float* __restrict__ xw)
{
    int tid = threadIdx.x;
    int lane = tid & 63, wv = tid >> 6;
    int lr = lane & 15, lk = lane >> 4;
    int r0 = (blockIdx.x*4 + wv) * 32;

    bf16x8 a[2][12];
    #pragma unroll
    for (int m=0;m<2;m++)
        #pragma unroll
        for (int kc=0;kc<12;kc++)
            a[m][kc] = *(const bf16x8*)(A + (size_t)(r0+m*16+lr)*384 + kc*32 + lk*8);

    for (int jg=0; jg<16; jg++){
        f32x4 acc[2][4];
        #pragma unroll
        for (int g=0; g<4; g++){
            float bias = b_ih[g*256 + jg*16 + lr];
            f32x4 v = {bias,bias,bias,bias};
            acc[0][g]=v; acc[1][g]=v;
        }
        #pragma unroll
        for (int kc=0; kc<12; kc++){
            bf16x8 b0 = *(const bf16x8*)(pwih + (size_t)(((jg*4+0)*12+kc)*64+lane)*8);
            bf16x8 b1 = *(const bf16x8*)(pwih + (size_t)(((jg*4+1)*12+kc)*64+lane)*8);
            bf16x8 b2 = *(const bf16x8*)(pwih + (size_t)(((jg*4+2)*12+kc)*64+lane)*8);
            bf16x8 b3 = *(const bf16x8*)(pwih + (size_t)(((jg*4+3)*12+kc)*64+lane)*8);
            #pragma unroll
            for (int m=0;m<2;m++){
                acc[m][0] = MFMA(a[m][kc], b0, acc[m][0]);
                acc[m][1] = MFMA(a[m][kc], b1, acc[m][1]);
                acc[m][2] = MFMA(a[m][kc], b2, acc[m][2]);
                acc[m][3] = MFMA(a[m][kc], b3, acc[m][3]);
            }
        }
        #pragma unroll
        for (int m=0;m<2;m++)
            #pragma unroll
            for (int g=0;g<4;g++)
                #pragma unroll
                for (int r=0;r<4;r++)
                    xw[(size_t)(r0+m*16+lk*4+r)*1024 + (jg*4+g)*16 + lr] = acc[m][g][r];
    }
}

// ---------------- pairwise persistent LSTM (L3-coherent handshake) ----------------
// 32 blocks: pair p = blk>>1 owns batches p*16..+15; half = blk&1 owns
// j in [half*128, half*128+128). W_hh half in registers. Per step:
// MFMA -> act -> sc1 h-store -> vmcnt0 -> barrier -> relaxed flag ->
// (prefetch xw) -> per-wave poll -> sc1 h-reload. No L2 wb/inv anywhere.
__global__ __launch_bounds__(256,1) void k_lstm_pair(
    const float* __restrict__ xw, const u16* __restrict__ pwhh,
    const float* __restrict__ W_dt, const float* __restrict__ dtv,
    u16* __restrict__ hb0, u16* __restrict__ hb1,
    float* __restrict__ hout, float* __restrict__ cout,
    unsigned int* __restrict__ flags)
{
    int tid = threadIdx.x;
    int lane = tid & 63, wv = tid >> 6;
    int lr = lane & 15, lk = lane >> 4;
    int blk = blockIdx.x;
    int p = blk >> 1, hf = blk & 1;
    int bb0 = p*16;
    int jg0 = hf*8 + wv*2;

    // W_hh fragments for this wave's 2 jg groups x 4 gates
    bf16x8 bfr[2][4][8];
    #pragma unroll
    for (int jl=0;jl<2;jl++)
        #pragma unroll
        for (int g=0;g<4;g++)
            #pragma unroll
            for (int kc=0;kc<8;kc++)
                bfr[jl][g][kc] = *(const bf16x8*)(pwhh + (size_t)((((jg0+jl)*4+g)*8+kc)*64+lane)*8);

    float wdt0 = W_dt[jg0*16 + lr];
    float wdt1 = W_dt[(jg0+1)*16 + lr];

    float cst[2][4] = {{0.f,0.f,0.f,0.f},{0.f,0.f,0.f,0.f}};
    bf16x8 a[8];
    #pragma unroll
    for (int kc=0;kc<8;kc++) a[kc] = (bf16x8)(short)0;

    int bth = bb0 + lk*4;

    float xwn[2][4][4];
    #pragma unroll
    for (int jl=0;jl<2;jl++)
        #pragma unroll
        for (int g=0;g<4;g++)
            #pragma unroll
            for (int r=0;r<4;r++)
                xwn[jl][g][r] = xw[(size_t)((bth+r)*64)*1024 + ((jg0+jl)*4+g)*16 + lr];
    float4 dtn = *(const float4*)(dtv + bth);

    unsigned int* myflag   = &flags[blk*64];
    unsigned int* partflag = &flags[(blk^1)*64];

    for (int t=0; t<64; t++){
        // a[] (inline-asm loads) + xwn prefetch must be complete
        asm volatile("s_waitcnt vmcnt(0)" ::: "memory");
        __builtin_amdgcn_sched_barrier(0);

        f32x4 acc[2][4];
        #pragma unroll
        for (int jl=0;jl<2;jl++)
            #pragma unroll
            for (int g=0;g<4;g++){
                f32x4 v;
                v[0]=xwn[jl][g][0]; v[1]=xwn[jl][g][1];
                v[2]=xwn[jl][g][2]; v[3]=xwn[jl][g][3];
                acc[jl][g] = v;
            }

        #pragma unroll
        for (int kc=0; kc<8; kc++){
            #pragma unroll
            for (int jl=0;jl<2;jl++){
                acc[jl][0] = MFMA(a[kc], bfr[jl][0][kc], acc[jl][0]);
                acc[jl][1] = MFMA(a[kc], bfr[jl][1][kc], acc[jl][1]);
                acc[jl][2] = MFMA(a[kc], bfr[jl][2][kc], acc[jl][2]);
                acc[jl][3] = MFMA(a[kc], bfr[jl][3][kc], acc[jl][3]);
            }
        }

        u16* hw = (t&1) ? hb1 : hb0;
        #pragma unroll
        for (int jl=0;jl<2;jl++){
            float wdt = jl ? wdt1 : wdt0;
            int jcol = (jg0+jl)*16 + lr;
            #pragma unroll
            for (int r=0;r<4;r++){
                float dd = (r==0)?dtn.x:(r==1)?dtn.y:(r==2)?dtn.z:dtn.w;
                float gi = sigm(acc[jl][0][r]);
                float gf = sigm(acc[jl][1][r] + wdt*dd);
                float gg = tanhfast(acc[jl][2][r]);
                float go = sigm(acc[jl][3][r]);
                float cn = fmaf(gf, cst[jl][r], gi*gg);
                cst[jl][r] = cn;
                float hv = go * tanhfast(cn);
                if (t < 63){
                    st_b16_sys(hw + (size_t)(bth+r)*256 + jcol, (unsigned)f2b(hv));
                } else {
                    hout[(size_t)(bth+r)*256 + jcol] = hv;
                    cout[(size_t)(bth+r)*256 + jcol] = cn;
                }
            }
        }

        if (t < 63){
            // own h slice visible at L3 before flag
            asm volatile("s_waitcnt vmcnt(0)" ::: "memory");
            __syncthreads();
            if (tid == 0)
                __hip_atomic_store(myflag, (unsigned)(t+1),
                                   __ATOMIC_RELAXED, __HIP_MEMORY_SCOPE_SYSTEM);

            // prefetch next xw/dt (plain cached loads; overlap the poll)
            #pragma unroll
            for (int jl=0;jl<2;jl++)
                #pragma unroll
                for (int g=0;g<4;g++)
                    #pragma unroll
                    for (int r=0;r<4;r++)
                        xwn[jl][g][r] = xw[(size_t)((bth+r)*64 + (t+1))*1024 + ((jg0+jl)*4+g)*16 + lr];
            dtn = *(const float4*)(dtv + (t+1)*256 + bth);

            if (lane == 0){
                while (__hip_atomic_load(partflag, __ATOMIC_RELAXED,
                                         __HIP_MEMORY_SCOPE_SYSTEM) < (unsigned)(t+1)) {}
            }
            __builtin_amdgcn_wave_barrier();

            const u16* hr = (t&1) ? hb1 : hb0;
            #pragma unroll
            for (int kc=0; kc<8; kc++)
                a[kc] = ld_b128_sys(hr + (size_t)(bb0+lr)*256 + kc*32 + lk*8);
        }
    }
}

// ---------------- heads (fp32) ----------------
__device__ __forceinline__ void dense30(
    const float* in, int istride,
    const float* __restrict__ W, int wstride, int K,
    const float* __restrict__ bias, const float* extra,
    float* outp, int ostride, bool relu, int j, int rh)
{
    float acc[15];
    #pragma unroll
    for (int i=0;i<15;i++) acc[i]=0.f;
    const float* w = W + j*wstride;
    for (int k=0;k<K;k+=4){
        float4 wv = *(const float4*)(w+k);
        #pragma unroll
        for (int i=0;i<15;i++){
            float4 xv = *(const float4*)(in + (rh+2*i)*istride + k);
            acc[i] = fmaf(wv.x,xv.x,acc[i]);
            acc[i] = fmaf(wv.y,xv.y,acc[i]);
            acc[i] = fmaf(wv.z,xv.z,acc[i]);
            acc[i] = fmaf(wv.w,xv.w,acc[i]);
        }
    }
    float bb = bias[j] + (extra ? extra[j] : 0.f);
    #pragma unroll
    for (int i=0;i<15;i++){
        float v = acc[i]+bb;
        outp[(rh+2*i)*ostride+j] = relu ? fmaxf(v,0.f) : v;
    }
}

__device__ __forceinline__ float dense1(
    const float* in, const float* __restrict__ W,
    const float* __restrict__ bias, int K, int j)
{
    const float* w = W + j*K;
    float s = 0.f;
    for (int k=0;k<K;k+=4){
        float4 wv = *(const float4*)(w+k);
        float4 xv = *(const float4*)(in+k);
        s = fmaf(wv.x,xv.x,s); s = fmaf(wv.y,xv.y,s);
        s = fmaf(wv.z,xv.z,s); s = fmaf(wv.w,xv.w,s);
    }
    return s + bias[j];
}

__global__ __launch_bounds__(256) void k_heads(
    const float* __restrict__ h, const float* __restrict__ cbuf,
    const float* __restrict__ rl,
    const float* __restrict__ a_w0, const float* __restrict__ a_b0,
    const float* __restrict__ a_w1, const float* __restrict__ a_b1,
    const float* __restrict__ c_w0, const float* __restrict__ c_b0,
    const float* __restrict__ c_w1, const float* __restrict__ c_b1,
    const float* __restrict__ log_std,
    float* __restrict__ out)
{
    __shared__ __align__(16) float hv[LH];
    __shared__ __align__(16) float rls[NR][HD];
    __shared__ __align__(16) float hid[NR][HD];
    __shared__ __align__(16) float dot2[HD];
    __shared__ __align__(16) float red[128];

    int b = blockIdx.x, tid = threadIdx.x;
    hv[tid] = h[b*LH + tid];
    for (int idx=tid; idx<NR*HD; idx+=256) rls[idx>>7][idx&127] = rl[(size_t)b*NR*HD + idx];
    __syncthreads();

    if (tid < 128){
        const float* w = a_w0 + tid*LIN + HD;
        float s = 0.f;
        for (int k=0;k<LH;k+=4){
            float4 wv = *(const float4*)(w+k);
            s = fmaf(wv.x,hv[k],s); s = fmaf(wv.y,hv[k+1],s);
            s = fmaf(wv.z,hv[k+2],s); s = fmaf(wv.w,hv[k+3],s);
        }
        dot2[tid] = s;
    }
    __syncthreads();

    int j = tid & 127, rh = tid >> 7;
    dense30(&rls[0][0], HD, a_w0, LIN, HD, a_b0, dot2, &hid[0][0], HD, true, j, rh);
    __syncthreads();

    if (tid < 60){
        int r = tid >> 1, o = tid & 1;
        const float* w = a_w1 + o*HD;
        float s = a_b1[o];
        for (int k=0;k<HD;k++) s = fmaf(hid[r][k], w[k], s);
        out[AM_OFF + b*60 + tid] = s;
        out[ALS_OFF + b*60 + tid] = log_std[tid];
    }

    float term = 0.f;
    if (tid < 128) term = fmaxf(dense1(hv, c_w0, c_b0, LH, tid), 0.f) * c_w1[tid];
    if (tid < 128) red[tid] = term;
    __syncthreads();
    for (int s2=64; s2>0; s2>>=1){
        if (tid < s2) red[tid] += red[tid+s2];
        __syncthreads();
    }
    if (tid == 0) out[V_OFF + b] = red[0] + c_b1[0];

    out[H_OFF + b*LH + tid] = hv[tid];
    out[C_OFF + b*LH + tid] = cbuf[b*LH + tid];
}

extern "C" void kernel_launch(void* const* d_in, const int* in_sizes, int n_in,
                              void* d_out, int out_size, void* d_ws, size_t ws_size,
                              hipStream_t stream)
{
    const float* obs   = (const float*)d_in[0];
    const float* re_w0 = (const float*)d_in[1];
    const float* re_b0 = (const float*)d_in[2];
    const float* re_w1 = (const float*)d_in[3];
    const float* re_b1 = (const float*)d_in[4];
    const float* re_w2 = (const float*)d_in[5];
    const float* re_b2 = (const float*)d_in[6];
    const float* me_w0 = (const float*)d_in[7];
    const float* me_b0 = (const float*)d_in[8];
    const float* me_w1 = (const float*)d_in[9];
    const float* me_b1 = (const float*)d_in[10];
    const float* me_w2 = (const float*)d_in[11];
    const float* me_b2 = (const float*)d_in[12];
    const float* W_ih  = (const float*)d_in[13];
    const float* b_ih  = (const float*)d_in[14];
    const float* W_hh  = (const float*)d_in[15];
    const float* W_dt  = (const float*)d_in[16];
    const float* a_w0  = (const float*)d_in[17];
    const float* a_b0  = (const float*)d_in[18];
    const float* a_w1  = (const float*)d_in[19];
    const float* a_b1  = (const float*)d_in[20];
    const float* c_w0  = (const float*)d_in[21];
    const float* c_b0  = (const float*)d_in[22];
    const float* c_w1  = (const float*)d_in[23];
    const float* c_b1  = (const float*)d_in[24];
    const float* lstd  = (const float*)d_in[25];
    float* out = (float*)d_out;

    float* ws = (float*)d_ws;
    size_t off = 0;
    float* xw4  = ws + off; off += (size_t)16384*1024;
    float* hout = ws + off; off += (size_t)Bn*LH;
    float* cb   = ws + off; off += (size_t)Bn*LH;
    float* rl   = ws + off; off += (size_t)Bn*NR*HD;
    float* dtv  = ws + off; off += (size_t)16384;
    unsigned int* flags = (unsigned int*)(ws + off); off += 2048;

    u16* us = (u16*)(ws + off);
    size_t uo = 0;
    u16* li_bf = us + uo; uo += (size_t)16384*LIN;
    u16* pw0   = us + uo; uo += 128*32;
    u16* pw1   = us + uo; uo += 128*128;
    u16* pw2   = us + uo; uo += 128*128;
    u16* pm0   = us + uo; uo += 128*64;
    u16* pm1   = us + uo; uo += 128*128;
    u16* pm2   = us + uo; uo += 128*128;
    u16* pwih  = us + uo; uo += (size_t)1024*384;
    u16* pwhh  = us + uo; uo += (size_t)1024*256;
    u16* hb0   = us + uo; uo += (size_t)Bn*LH;
    u16* hb1   = us + uo; uo += (size_t)Bn*LH;

    hipMemsetAsync(flags, 0, 32*64*sizeof(unsigned int), stream);

    k_pack<<<16,   256, 0, stream>>>(re_w0, pw0, 128, 32, 32);
    k_pack<<<64,   256, 0, stream>>>(re_w1, pw1, 128, 128, 128);
    k_pack<<<64,   256, 0, stream>>>(re_w2, pw2, 128, 128, 128);
    k_pack<<<32,   256, 0, stream>>>(me_w0, pm0, 128, 40, 64);
    k_pack<<<64,   256, 0, stream>>>(me_w1, pm1, 128, 128, 128);
    k_pack<<<64,   256, 0, stream>>>(me_w2, pm2, 128, 128, 128);
    k_pack_gi<<<1536, 256, 0, stream>>>(W_ih, pwih, 384);
    k_pack_gi<<<1024, 256, 0, stream>>>(W_hh, pwhh, 256);
    k_dtv<<<64, 256, 0, stream>>>(obs, dtv);

    k_embed<<<16384, 256, 0, stream>>>(obs, pw0, re_b0, pw1, re_b1, pw2, re_b2,
                                       li_bf, rl);
    k_market<<<512, 256, 0, stream>>>(obs, pm0, me_b0, pm1, me_b1, pm2, me_b2,
                                      li_bf);
    k_xw<<<128, 256, 0, stream>>>(li_bf, pwih, b_ih, xw4);

    k_lstm_pair<<<32, 256, 0, stream>>>(xw4, pwhh, W_dt, dtv, hb0, hb1,
                                        hout, cb, flags);

    k_heads<<<256, 256, 0, stream>>>(hout, cb, rl,
        a_w0, a_b0, a_w1, a_b1, c_w0, c_b0, c_w1, c_b1, lstd, out);
}